// Round 8
// baseline (261.870 us; speedup 1.0000x reference)
//
#include <hip/hip_runtime.h>
#include <hip/hip_bf16.h>

typedef _Float16 half8_t __attribute__((ext_vector_type(8)));
typedef _Float16 half4_t __attribute__((ext_vector_type(4)));
typedef _Float16 half2_t __attribute__((ext_vector_type(2)));
typedef float    f32x4   __attribute__((ext_vector_type(4)));
typedef float    f32x16  __attribute__((ext_vector_type(16)));

#define CDIM 512
#define NHEAD 8
#define HD 64
#define NTOK 512
#define NWIN 64
#define TC 1536  // 3*C

// raw v_exp_f32 (2^x), no libm range guards; inputs here are always <= 11.5
// and large-negative underflows to 0 which is exactly what softmax wants.
__device__ __forceinline__ float fexp2(float x) {
  float r;
  asm("v_exp_f32 %0, %1" : "=v"(r) : "v"(x));
  return r;
}

// global->LDS direct DMA, 16B per lane, wave-uniform LDS base (m97 pattern)
#define GLL16(g, l)                                                        \
  __builtin_amdgcn_global_load_lds((const __attribute__((address_space(1))) void*)(g), \
                                   (__attribute__((address_space(3))) void*)(l), 16, 0, 0)

// ws panel layout: per (local window w): 24 panels of 32768 halfs (65536 B)
//   panel (w*24 + 0*8 + h): Q*log2e [n][d]  (later overwritten by attention output [n][d])
//   panel (w*24 + 1*8 + h): K  [n][d]
//   panel (w*24 + 2*8 + h): V key-permuted: [kg(32)][hh(2)][d(64)][e(8)]
//     key n -> kg=n>>4, hh=(n>>2)&1, e=(n&3)+4*((n>>3)&1)

// ---------------- x fp32 -> fp16 (one pass; removes per-use cvt in gemm1) ----------------
__global__ __launch_bounds__(256) void cvt_x(const float* __restrict__ x,
                                             _Float16* __restrict__ x16, int n8) {
  int i = blockIdx.x * 256 + threadIdx.x;
  if (i < n8) {
    float4 v0 = *(const float4*)(x + (size_t)i * 8);
    float4 v1 = *(const float4*)(x + (size_t)i * 8 + 4);
    half8_t h = {(_Float16)v0.x, (_Float16)v0.y, (_Float16)v0.z, (_Float16)v0.w,
                 (_Float16)v1.x, (_Float16)v1.y, (_Float16)v1.z, (_Float16)v1.w};
    *(half8_t*)(x16 + (size_t)i * 8) = h;
  }
}

// ---------------- prep: fp32 -> fp16 transposes via LDS tiles ----------------
__global__ __launch_bounds__(256) void prep_weights(
    const float* __restrict__ wqkv, const float* __restrict__ wproj,
    _Float16* __restrict__ wqkvT, _Float16* __restrict__ wprojT) {
  __shared__ _Float16 T[64 * 65];
  int b = blockIdx.x;
  const float* src; _Float16* dst; int Cc, r0, c0;
  if (b < 192) {  // wqkv [512][1536] -> wqkvT [1536][512]
    src = wqkv; dst = wqkvT; Cc = 1536;
    c0 = (b % 24) * 64; r0 = (b / 24) * 64;
  } else {        // wproj [512][512] -> wprojT [512][512]
    b -= 192; src = wproj; dst = wprojT; Cc = 512;
    c0 = (b & 7) * 64; r0 = (b >> 3) * 64;
  }
  const int t = threadIdx.x;
#pragma unroll
  for (int i = 0; i < 16; ++i) {
    int idx = i * 256 + t, rr = idx >> 6, cc = idx & 63;
    T[rr * 65 + cc] = (_Float16)src[(size_t)(r0 + rr) * Cc + c0 + cc];
  }
  __syncthreads();
#pragma unroll
  for (int i = 0; i < 2; ++i) {
    int idx = i * 256 + t, ol = idx >> 3, c8 = idx & 7;
    half8_t vv;
#pragma unroll
    for (int e = 0; e < 8; ++e) vv[e] = T[(c8 * 8 + e) * 65 + ol];
    *(half8_t*)(dst + (size_t)(c0 + ol) * 512 + r0 + c8 * 8) = vv;
  }
}

// ---------------- GEMM1 v3: global_load_lds both operands, dbuf, 1 barrier/K-step ----------------
__global__ __launch_bounds__(256) void gemm1_qkv(
    const _Float16* __restrict__ x16,
    const _Float16* __restrict__ wT,
    const float* __restrict__ bias,
    _Float16* __restrict__ qkv) {
  __shared__ __align__(16) _Float16 smem[4 * 128 * 64];  // As[2] 32KB | Bs[2] 32KB
  char* base = (char*)smem;
  const int tid = threadIdx.x;
  const int l = tid & 63;
  const int wid = tid >> 6;
  const int wr = wid >> 1, wc = wid & 1;
  const int lr = l & 15, g = l >> 4;
  const int swzf = (lr & 7) << 4;
  const int m0 = blockIdx.x * 128;
  const int cb = blockIdx.y * 128;  // channel base 0..1408
  const int j = cb >> 9;            // 0=Q 1=K 2=V

  const int srow = l >> 3;
  const int scol = 16 * ((l & 7) ^ srow);
  const size_t aRowB = (size_t)(m0 + srow) * 1024 + scol;
  const size_t bRowB = (size_t)(cb + srow) * 1024 + scol;

#define STAGE_G1(buf, k0)                                                         \
  {                                                                               \
    char* Ad = base + (buf)*16384 + wid * 4096;                                   \
    char* Bd = base + 32768 + (buf)*16384 + wid * 4096;                           \
    _Pragma("unroll") for (int i = 0; i < 4; ++i) {                               \
      int chunk = wid * 4 + i;                                                    \
      GLL16((const char*)x16 + aRowB + (size_t)chunk * 8192 + (k0)*2, Ad + i * 1024); \
      GLL16((const char*)wT + bRowB + (size_t)chunk * 8192 + (k0)*2, Bd + i * 1024);  \
    }                                                                             \
  }

  STAGE_G1(0, 0);
  __syncthreads();

  f32x4 acc[4][4] = {};
  for (int ks = 0; ks < 8; ++ks) {
    const int cur = ks & 1;
    if (ks < 7) STAGE_G1(cur ^ 1, (ks + 1) * 64);
    char* AsB = base + cur * 16384;
    char* BsB = base + 32768 + cur * 16384;
#pragma unroll
    for (int kk = 0; kk < 2; ++kk) {
      half8_t a[4], b[4];
#pragma unroll
      for (int mt = 0; mt < 4; ++mt) {
        int row = wr * 64 + mt * 16 + lr;
        a[mt] = *(const half8_t*)(AsB + row * 128 + ((kk * 64 + g * 16) ^ swzf));
      }
#pragma unroll
      for (int nt = 0; nt < 4; ++nt) {
        int row = wc * 64 + nt * 16 + lr;
        b[nt] = *(const half8_t*)(BsB + row * 128 + ((kk * 64 + g * 16) ^ swzf));
      }
#pragma unroll
      for (int mt = 0; mt < 4; ++mt)
#pragma unroll
        for (int nt = 0; nt < 4; ++nt)
          acc[mt][nt] = __builtin_amdgcn_mfma_f32_16x16x32_f16(a[mt], b[nt], acc[mt][nt], 0, 0, 0);
    }
    __syncthreads();
  }

  if (j == 2) {  // V: key-permuted panels, 8B stores
#pragma unroll
    for (int nt = 0; nt < 4; ++nt) {
      const int ch = cb + wc * 64 + nt * 16 + lr;
      const int h = (ch >> 6) & 7, d = ch & 63;
      const float bvs = bias[ch];
#pragma unroll
      for (int mt = 0; mt < 4; ++mt) {
        const int row = m0 + wr * 64 + mt * 16 + g * 4;
        const int wL = row >> 9, n = row & 511;
        _Float16* panel = qkv + ((size_t)(wL * 24 + 16 + h) << 15);
        const int kg = n >> 4, hh = (n >> 2) & 1, e4 = (n & 8) >> 1;
        half4_t pk = {(_Float16)(acc[mt][nt][0] + bvs), (_Float16)(acc[mt][nt][1] + bvs),
                      (_Float16)(acc[mt][nt][2] + bvs), (_Float16)(acc[mt][nt][3] + bvs)};
        *(half4_t*)(panel + ((size_t)(kg * 2 + hh) * 64 + d) * 8 + e4) = pk;
      }
    }
  } else {  // Q/K: acc -> swizzled LDS C-tile -> coalesced 16B stores
    // Q (j==0) is pre-scaled by log2e so attention can use exp2 directly.
    const float scl = (j == 0) ? 1.44269504f : 1.0f;
    char* CB = base;
#pragma unroll
    for (int nt = 0; nt < 4; ++nt) {
      const int chl = wc * 64 + nt * 16 + lr;
      const float bvs = bias[cb + chl];
#pragma unroll
      for (int mt = 0; mt < 4; ++mt) {
#pragma unroll
        for (int r = 0; r < 4; ++r) {
          int nl = wr * 64 + mt * 16 + g * 4 + r;
          *(_Float16*)(CB + nl * 256 + ((chl * 2) ^ ((nl & 7) << 5))) =
              (_Float16)((acc[mt][nt][r] + bvs) * scl);
        }
      }
    }
    __syncthreads();
#pragma unroll
    for (int i = 0; i < 8; ++i) {
      int idx = i * 256 + tid, nl = idx >> 4, c8 = idx & 15;
      half8_t vv = *(const half8_t*)(CB + nl * 256 + ((c8 * 16) ^ ((nl & 7) << 5)));
      int chg = cb + c8 * 8;
      int h = (chg >> 6) & 7, d = chg & 63;
      int ng = m0 + nl, wL = ng >> 9, nn = ng & 511;
      _Float16* panel = qkv + ((size_t)(wL * 24 + j * 8 + h) << 15);
      *(half8_t*)(panel + (size_t)nn * 64 + d) = vv;
    }
  }
}

// ---------------- attention v5: swapped QK^T, raw v_exp, max3 tree, XCD-grouped ----------------
// grid = dim3(nw*8, 4): blockIdx.x = w*8+h (group), blockIdx.y = qc.
__global__ __launch_bounds__(256) void attn_win(_Float16* __restrict__ qkv) {
  const int tid = threadIdx.x;
  const int l = tid & 63;
  const int wid = tid >> 6;
  const int q32 = l & 31;
  const int h2 = l >> 5;
  const int wh = blockIdx.x;
  const int qc = blockIdx.y;
  const int h = wh & 7;
  const int w = wh >> 3;
  _Float16* Qp = qkv + ((size_t)(w * 24 + h) << 15);
  const _Float16* Kp = qkv + ((size_t)(w * 24 + 8 + h) << 15);
  const _Float16* Vp = qkv + ((size_t)(w * 24 + 16 + h) << 15);
  const int qrow = qc * 128 + wid * 32 + q32;

  half8_t qf[4];  // Q (pre-scaled by log2e) B-frags
#pragma unroll
  for (int j = 0; j < 4; ++j)
    qf[j] = *(const half8_t*)(Qp + (size_t)qrow * 64 + j * 16 + h2 * 8);

  f32x16 o0 = {}, o1 = {};
  float m_run = -1e30f, lsum = 0.f;

  half8_t kf[4];
#pragma unroll
  for (int j = 0; j < 4; ++j)
    kf[j] = *(const half8_t*)(Kp + (size_t)q32 * 64 + j * 16 + h2 * 8);

#pragma unroll 2
  for (int kt = 0; kt < 16; ++kt) {
    // early loads: V(kt) flies under QK^T+softmax; K(kt+1) under the whole iter
    const _Float16* vb = Vp + (size_t)(kt * 4 + h2) * 512 + q32 * 8;
    half8_t vf0 = *(const half8_t*)(vb);
    half8_t vf1 = *(const half8_t*)(vb + 256);
    half8_t vf2 = *(const half8_t*)(vb + 1024);
    half8_t vf3 = *(const half8_t*)(vb + 1280);
    half8_t kn[4];
    if (kt < 15) {
      const _Float16* kb = Kp + (size_t)(kt * 32 + 32 + q32) * 64 + h2 * 8;
#pragma unroll
      for (int j = 0; j < 4; ++j) kn[j] = *(const half8_t*)(kb + j * 16);
    }

    __builtin_amdgcn_s_setprio(1);
    f32x16 s = {};
#pragma unroll
    for (int j = 0; j < 4; ++j)
      s = __builtin_amdgcn_mfma_f32_32x32x16_f16(kf[j], qf[j], s, 0, 0, 0);
    __builtin_amdgcn_s_setprio(0);

    // lane-local max over 16 keys via v_max3 tree, + partner half
    float ma = fmaxf(fmaxf(s[0], s[1]), s[2]);
    float mb = fmaxf(fmaxf(s[3], s[4]), s[5]);
    float mc = fmaxf(fmaxf(s[6], s[7]), s[8]);
    float md = fmaxf(fmaxf(s[9], s[10]), s[11]);
    float me = fmaxf(fmaxf(s[12], s[13]), s[14]);
    float mf_ = fmaxf(fmaxf(ma, mb), mc);
    float mg = fmaxf(fmaxf(md, me), s[15]);
    float tmax = fmaxf(mf_, mg);
    tmax = fmaxf(tmax, __shfl_xor(tmax, 32));
    if (!__all(tmax <= m_run + 11.5f)) {  // defer-max: p bounded by 2^11.5, fp16-safe
      float mNew = fmaxf(m_run, tmax);
      float sc = fexp2(m_run - mNew);
      lsum *= sc;
#pragma unroll
      for (int r = 0; r < 16; ++r) { o0[r] *= sc; o1[r] *= sc; }
      m_run = mNew;
    }
    half8_t pf0, pf1;
    float tsum = 0.f;
#pragma unroll
    for (int e = 0; e < 4; ++e) {
      float a0 = fexp2(s[2 * e] - m_run), a1 = fexp2(s[2 * e + 1] - m_run);
      tsum += a0 + a1;
      ((half2_t*)&pf0)[e] = __builtin_bit_cast(half2_t, __builtin_amdgcn_cvt_pkrtz(a0, a1));
    }
#pragma unroll
    for (int e = 0; e < 4; ++e) {
      float a0 = fexp2(s[8 + 2 * e] - m_run), a1 = fexp2(s[9 + 2 * e] - m_run);
      tsum += a0 + a1;
      ((half2_t*)&pf1)[e] = __builtin_bit_cast(half2_t, __builtin_amdgcn_cvt_pkrtz(a0, a1));
    }
    tsum += __shfl_xor(tsum, 32);
    lsum += tsum;

    __builtin_amdgcn_s_setprio(1);
    o0 = __builtin_amdgcn_mfma_f32_32x32x16_f16(vf0, pf0, o0, 0, 0, 0);
    o1 = __builtin_amdgcn_mfma_f32_32x32x16_f16(vf1, pf0, o1, 0, 0, 0);
    o0 = __builtin_amdgcn_mfma_f32_32x32x16_f16(vf2, pf1, o0, 0, 0, 0);
    o1 = __builtin_amdgcn_mfma_f32_32x32x16_f16(vf3, pf1, o1, 0, 0, 0);
    __builtin_amdgcn_s_setprio(0);
#pragma unroll
    for (int j = 0; j < 4; ++j) kf[j] = kn[j];
  }
  const float inv = 1.0f / lsum;
#pragma unroll
  for (int rq = 0; rq < 4; ++rq) {
    half4_t v0, v1;
#pragma unroll
    for (int i = 0; i < 4; ++i) {
      v0[i] = (_Float16)(o0[rq * 4 + i] * inv);
      v1[i] = (_Float16)(o1[rq * 4 + i] * inv);
    }
    *(half4_t*)(Qp + (size_t)qrow * 64 + 8 * rq + 4 * h2) = v0;
    *(half4_t*)(Qp + (size_t)qrow * 64 + 32 + 8 * rq + 4 * h2) = v1;
  }
}

// ---------------- GEMM2: out = attn_out @ Wproj + b, k-prefetched fragments ----------------
__global__ __launch_bounds__(256) void gemm2_proj(
    const _Float16* __restrict__ qkv,
    const _Float16* __restrict__ wpT,  // [512][512]
    const float* __restrict__ bias,    // [512]
    float* __restrict__ out) {
  const int tid = threadIdx.x, l = tid & 63;
  const int wid = tid >> 6, wr = wid >> 1, wc = wid & 1;
  const int lr = l & 15, lk8 = (l >> 4) * 8;
  const int m0 = blockIdx.x * 128, n0 = blockIdx.y * 128;
  size_t aBase[4];
#pragma unroll
  for (int mt = 0; mt < 4; ++mt) {
    int row = m0 + wr * 64 + mt * 16 + lr;
    int wL = row >> 9, n = row & 511;
    aBase[mt] = ((size_t)(wL * 24) << 15) + (size_t)n * 64 + lk8;
  }
  size_t bBase[4];
#pragma unroll
  for (int nt = 0; nt < 4; ++nt)
    bBase[nt] = (size_t)(n0 + wc * 64 + nt * 16 + lr) * 512 + lk8;

  half8_t a[4], b[4];
#pragma unroll
  for (int mt = 0; mt < 4; ++mt) a[mt] = *(const half8_t*)(qkv + aBase[mt]);
#pragma unroll
  for (int nt = 0; nt < 4; ++nt) b[nt] = *(const half8_t*)(wpT + bBase[nt]);

  f32x4 acc[4][4] = {};
#pragma unroll 2
  for (int ks = 0; ks < 16; ++ks) {
    half8_t an[4], bn[4];
    if (ks < 15) {  // prefetch ks+1 fragments; they fly under the 16 MFMAs below
      const size_t aoff = (size_t)((ks + 1) >> 1) * 32768 + (size_t)((ks + 1) & 1) * 32;
#pragma unroll
      for (int mt = 0; mt < 4; ++mt) an[mt] = *(const half8_t*)(qkv + aBase[mt] + aoff);
#pragma unroll
      for (int nt = 0; nt < 4; ++nt) bn[nt] = *(const half8_t*)(wpT + bBase[nt] + (ks + 1) * 32);
    }
#pragma unroll
    for (int mt = 0; mt < 4; ++mt)
#pragma unroll
      for (int nt = 0; nt < 4; ++nt)
        acc[mt][nt] = __builtin_amdgcn_mfma_f32_16x16x32_f16(a[mt], b[nt], acc[mt][nt], 0, 0, 0);
#pragma unroll
    for (int i = 0; i < 4; ++i) { a[i] = an[i]; b[i] = bn[i]; }
  }
#pragma unroll
  for (int nt = 0; nt < 4; ++nt) {
    int col = n0 + wc * 64 + nt * 16 + lr;
    float bv = bias[col];
#pragma unroll
    for (int mt = 0; mt < 4; ++mt) {
      int row = m0 + wr * 64 + mt * 16 + ((l >> 4) << 2);
#pragma unroll
      for (int r = 0; r < 4; ++r)
        out[(size_t)(row + r) * 512 + col] = acc[mt][nt][r] + bv;
    }
  }
}

extern "C" void kernel_launch(void* const* d_in, const int* in_sizes, int n_in,
                              void* d_out, int out_size, void* d_ws, size_t ws_size,
                              hipStream_t stream) {
  const float* x = (const float*)d_in[0];
  const float* wqkv = (const float*)d_in[1];
  const float* bqkv = (const float*)d_in[2];
  const float* wproj = (const float*)d_in[3];
  const float* bproj = (const float*)d_in[4];
  float* out = (float*)d_out;

  _Float16* wqkvT = (_Float16*)d_ws;
  _Float16* wprojT = wqkvT + (size_t)TC * CDIM;
  _Float16* chunkws = wprojT + (size_t)CDIM * CDIM;
  const size_t fixed = ((size_t)TC * CDIM + (size_t)CDIM * CDIM) * sizeof(_Float16);
  const size_t perwin = ((size_t)NTOK * CDIM + (size_t)24 * 32768) * sizeof(_Float16);
  int nw = 64;
  while (nw > 1 && fixed + (size_t)nw * perwin > ws_size) nw >>= 1;

  prep_weights<<<dim3(256), 256, 0, stream>>>(wqkv, wproj, wqkvT, wprojT);
  for (int wbase = 0; wbase < NWIN; wbase += nw) {
    const float* xc = x + (size_t)wbase * NTOK * CDIM;
    float* oc = out + (size_t)wbase * NTOK * CDIM;
    _Float16* x16 = chunkws;
    _Float16* qkvws = chunkws + (size_t)nw * NTOK * CDIM;
    const int n8 = nw * NTOK * CDIM / 8;
    cvt_x<<<dim3((n8 + 255) / 256), 256, 0, stream>>>(xc, x16, n8);
    gemm1_qkv<<<dim3(nw * 4, 12), 256, 0, stream>>>(x16, wqkvT, bqkv, qkvws);
    attn_win<<<dim3(nw * 8, 4), 256, 0, stream>>>(qkvws);
    gemm2_proj<<<dim3(nw * 4, 4), 256, 0, stream>>>(qkvws, wprojT, bproj, oc);
  }
}

// Round 10
// 233.584 us; speedup vs baseline: 1.1211x; 1.1211x over previous
//
#include <hip/hip_runtime.h>
#include <hip/hip_bf16.h>

typedef _Float16 half8_t __attribute__((ext_vector_type(8)));
typedef _Float16 half4_t __attribute__((ext_vector_type(4)));
typedef _Float16 half2_t __attribute__((ext_vector_type(2)));
typedef float    f32x4   __attribute__((ext_vector_type(4)));
typedef float    f32x16  __attribute__((ext_vector_type(16)));

#define CDIM 512
#define NHEAD 8
#define HD 64
#define NTOK 512
#define NWIN 64
#define TC 1536  // 3*C

// raw v_exp_f32 (2^x); softmax inputs <= 11.5, large-negative underflows to 0.
__device__ __forceinline__ float fexp2(float x) {
  float r;
  asm("v_exp_f32 %0, %1" : "=v"(r) : "v"(x));
  return r;
}

// global->LDS direct DMA, 16B per lane, wave-uniform LDS base (m97 pattern)
#define GLL16(g, l)                                                        \
  __builtin_amdgcn_global_load_lds((const __attribute__((address_space(1))) void*)(g), \
                                   (__attribute__((address_space(3))) void*)(l), 16, 0, 0)

// ws panel layout: per (local window w): 24 panels of 32768 halfs (65536 B)
//   panel (w*24 + 0*8 + h): Q*log2e [n][d]  (later overwritten by attention output [n][d])
//   panel (w*24 + 1*8 + h): K  [n][d]
//   panel (w*24 + 2*8 + h): V key-permuted: [kg(32)][hh(2)][d(64)][e(8)]
//     key n -> kg=n>>4, hh=(n>>2)&1, e=(n&3)+4*((n>>3)&1)

// ---------------- x fp32 -> fp16 ----------------
__global__ __launch_bounds__(256) void cvt_x(const float* __restrict__ x,
                                             _Float16* __restrict__ x16, int n8) {
  int i = blockIdx.x * 256 + threadIdx.x;
  if (i < n8) {
    float4 v0 = *(const float4*)(x + (size_t)i * 8);
    float4 v1 = *(const float4*)(x + (size_t)i * 8 + 4);
    half8_t h = {(_Float16)v0.x, (_Float16)v0.y, (_Float16)v0.z, (_Float16)v0.w,
                 (_Float16)v1.x, (_Float16)v1.y, (_Float16)v1.z, (_Float16)v1.w};
    *(half8_t*)(x16 + (size_t)i * 8) = h;
  }
}

// ---------------- prep: fp32 -> fp16 transposes via LDS tiles ----------------
__global__ __launch_bounds__(256) void prep_weights(
    const float* __restrict__ wqkv, const float* __restrict__ wproj,
    _Float16* __restrict__ wqkvT, _Float16* __restrict__ wprojT) {
  __shared__ _Float16 T[64 * 65];
  int b = blockIdx.x;
  const float* src; _Float16* dst; int Cc, r0, c0;
  if (b < 192) {
    src = wqkv; dst = wqkvT; Cc = 1536;
    c0 = (b % 24) * 64; r0 = (b / 24) * 64;
  } else {
    b -= 192; src = wproj; dst = wprojT; Cc = 512;
    c0 = (b & 7) * 64; r0 = (b >> 3) * 64;
  }
  const int t = threadIdx.x;
#pragma unroll
  for (int i = 0; i < 16; ++i) {
    int idx = i * 256 + t, rr = idx >> 6, cc = idx & 63;
    T[rr * 65 + cc] = (_Float16)src[(size_t)(r0 + rr) * Cc + c0 + cc];
  }
  __syncthreads();
#pragma unroll
  for (int i = 0; i < 2; ++i) {
    int idx = i * 256 + t, ol = idx >> 3, c8 = idx & 7;
    half8_t vv;
#pragma unroll
    for (int e = 0; e < 8; ++e) vv[e] = T[(c8 * 8 + e) * 65 + ol];
    *(half8_t*)(dst + (size_t)(c0 + ol) * 512 + r0 + c8 * 8) = vv;
  }
}

// ---------------- GEMM1 v3: global_load_lds both operands, dbuf, 1 barrier/K-step ----------------
__global__ __launch_bounds__(256) void gemm1_qkv(
    const _Float16* __restrict__ x16,
    const _Float16* __restrict__ wT,
    const float* __restrict__ bias,
    _Float16* __restrict__ qkv) {
  __shared__ __align__(16) _Float16 smem[4 * 128 * 64];
  char* base = (char*)smem;
  const int tid = threadIdx.x;
  const int l = tid & 63;
  const int wid = tid >> 6;
  const int wr = wid >> 1, wc = wid & 1;
  const int lr = l & 15, g = l >> 4;
  const int swzf = (lr & 7) << 4;
  const int m0 = blockIdx.x * 128;
  const int cb = blockIdx.y * 128;
  const int j = cb >> 9;

  const int srow = l >> 3;
  const int scol = 16 * ((l & 7) ^ srow);
  const size_t aRowB = (size_t)(m0 + srow) * 1024 + scol;
  const size_t bRowB = (size_t)(cb + srow) * 1024 + scol;

#define STAGE_G1(buf, k0)                                                         \
  {                                                                               \
    char* Ad = base + (buf)*16384 + wid * 4096;                                   \
    char* Bd = base + 32768 + (buf)*16384 + wid * 4096;                           \
    _Pragma("unroll") for (int i = 0; i < 4; ++i) {                               \
      int chunk = wid * 4 + i;                                                    \
      GLL16((const char*)x16 + aRowB + (size_t)chunk * 8192 + (k0)*2, Ad + i * 1024); \
      GLL16((const char*)wT + bRowB + (size_t)chunk * 8192 + (k0)*2, Bd + i * 1024);  \
    }                                                                             \
  }

  STAGE_G1(0, 0);
  __syncthreads();

  f32x4 acc[4][4] = {};
  for (int ks = 0; ks < 8; ++ks) {
    const int cur = ks & 1;
    if (ks < 7) STAGE_G1(cur ^ 1, (ks + 1) * 64);
    char* AsB = base + cur * 16384;
    char* BsB = base + 32768 + cur * 16384;
#pragma unroll
    for (int kk = 0; kk < 2; ++kk) {
      half8_t a[4], b[4];
#pragma unroll
      for (int mt = 0; mt < 4; ++mt) {
        int row = wr * 64 + mt * 16 + lr;
        a[mt] = *(const half8_t*)(AsB + row * 128 + ((kk * 64 + g * 16) ^ swzf));
      }
#pragma unroll
      for (int nt = 0; nt < 4; ++nt) {
        int row = wc * 64 + nt * 16 + lr;
        b[nt] = *(const half8_t*)(BsB + row * 128 + ((kk * 64 + g * 16) ^ swzf));
      }
#pragma unroll
      for (int mt = 0; mt < 4; ++mt)
#pragma unroll
        for (int nt = 0; nt < 4; ++nt)
          acc[mt][nt] = __builtin_amdgcn_mfma_f32_16x16x32_f16(a[mt], b[nt], acc[mt][nt], 0, 0, 0);
    }
    __syncthreads();
  }

  if (j == 2) {  // V: key-permuted panels, 8B stores
#pragma unroll
    for (int nt = 0; nt < 4; ++nt) {
      const int ch = cb + wc * 64 + nt * 16 + lr;
      const int h = (ch >> 6) & 7, d = ch & 63;
      const float bvs = bias[ch];
#pragma unroll
      for (int mt = 0; mt < 4; ++mt) {
        const int row = m0 + wr * 64 + mt * 16 + g * 4;
        const int wL = row >> 9, n = row & 511;
        _Float16* panel = qkv + ((size_t)(wL * 24 + 16 + h) << 15);
        const int kg = n >> 4, hh = (n >> 2) & 1, e4 = (n & 8) >> 1;
        half4_t pk = {(_Float16)(acc[mt][nt][0] + bvs), (_Float16)(acc[mt][nt][1] + bvs),
                      (_Float16)(acc[mt][nt][2] + bvs), (_Float16)(acc[mt][nt][3] + bvs)};
        *(half4_t*)(panel + ((size_t)(kg * 2 + hh) * 64 + d) * 8 + e4) = pk;
      }
    }
  } else {  // Q/K: acc -> swizzled LDS C-tile -> coalesced 16B stores
    const float scl = (j == 0) ? 1.44269504f : 1.0f;
    char* CB = base;
#pragma unroll
    for (int nt = 0; nt < 4; ++nt) {
      const int chl = wc * 64 + nt * 16 + lr;
      const float bvs = bias[cb + chl];
#pragma unroll
      for (int mt = 0; mt < 4; ++mt) {
#pragma unroll
        for (int r = 0; r < 4; ++r) {
          int nl = wr * 64 + mt * 16 + g * 4 + r;
          *(_Float16*)(CB + nl * 256 + ((chl * 2) ^ ((nl & 7) << 5))) =
              (_Float16)((acc[mt][nt][r] + bvs) * scl);
        }
      }
    }
    __syncthreads();
#pragma unroll
    for (int i = 0; i < 8; ++i) {
      int idx = i * 256 + tid, nl = idx >> 4, c8 = idx & 15;
      half8_t vv = *(const half8_t*)(CB + nl * 256 + ((c8 * 16) ^ ((nl & 7) << 5)));
      int chg = cb + c8 * 8;
      int h = (chg >> 6) & 7, d = chg & 63;
      int ng = m0 + nl, wL = ng >> 9, nn = ng & 511;
      _Float16* panel = qkv + ((size_t)(wL * 24 + j * 8 + h) << 15);
      *(half8_t*)(panel + (size_t)nn * 64 + d) = vv;
    }
  }
}

// ---------------- attention v6b: LDS K/V ring, airtight vmcnt ledger ----------------
// grid = dim3(nw*8, 4). Block = 4 waves on one (w,h); ring of 4 slots x 8KB
//   slot: [K 4KB swizzled (pair: pre-swz source / swz read)] [V 4KB linear].
// Ledger: qf drained up-front; only slot DMAs (2/slot/wave) counted. Per iter:
//   vmcnt(N,"memory") -> sched_barrier -> s_barrier("memory") -> issue slot KT+3 -> reads.
// Issue AFTER the barrier so slot (KT+3)&3 == (KT-1)&3 is overwritten only once all
// waves' reads of slot KT-1 (consumed before this barrier) are done.
__global__ __launch_bounds__(256) void attn_win(_Float16* __restrict__ qkv) {
  __shared__ __align__(16) char ring[4 * 8192];
  char* ringB = ring;
  const int tid = threadIdx.x;
  const int l = tid & 63;
  const int wid = tid >> 6;
  const int q32 = l & 31;
  const int h2 = l >> 5;
  const int wh = blockIdx.x;
  const int qc = blockIdx.y;
  const int h = wh & 7;
  const int w = wh >> 3;
  _Float16* Qp = qkv + ((size_t)(w * 24 + h) << 15);
  const _Float16* Kp = qkv + ((size_t)(w * 24 + 8 + h) << 15);
  const _Float16* Vp = qkv + ((size_t)(w * 24 + 16 + h) << 15);
  const int qrow = qc * 128 + wid * 32 + q32;

  // K stage source pre-swizzle (write side of rule-21 pair)
  const size_t kSrc = (size_t)(l >> 3) * 128 + (size_t)((l & 7) ^ (l >> 3)) * 16;
  // K fragment read offsets (read side)
  const int kof0 = ((0 * 2 + h2) ^ (q32 & 7)) << 4;
  const int kof1 = ((1 * 2 + h2) ^ (q32 & 7)) << 4;
  const int kof2 = ((2 * 2 + h2) ^ (q32 & 7)) << 4;
  const int kof3 = ((3 * 2 + h2) ^ (q32 & 7)) << 4;
  const int voff = 4096 + h2 * 1024 + q32 * 16;

  // wave wid: wid<2 stages K chunks {wid*2,+1}; wid>=2 stages V chunks. 2 DMAs/slot/wave.
#define ISSUE_SLOT(KT)                                                            \
  {                                                                               \
    char* sb = ringB + ((KT)&3) * 8192;                                           \
    if (wid < 2) {                                                                \
      _Pragma("unroll") for (int i = 0; i < 2; ++i) {                             \
        int u = wid * 2 + i;                                                      \
        GLL16((const char*)Kp + (size_t)(KT)*4096 + (size_t)u * 1024 + kSrc,      \
              sb + u * 1024);                                                     \
      }                                                                           \
    } else {                                                                      \
      _Pragma("unroll") for (int i = 0; i < 2; ++i) {                             \
        int u = (wid - 2) * 2 + i;                                                \
        GLL16((const char*)Vp + (size_t)(KT)*4096 + (size_t)u * 1024 + l * 16,    \
              sb + 4096 + u * 1024);                                              \
      }                                                                           \
    }                                                                             \
  }

  half8_t qf[4];  // Q (pre-scaled by log2e) B-frags
#pragma unroll
  for (int j = 0; j < 4; ++j)
    qf[j] = *(const half8_t*)(Qp + (size_t)qrow * 64 + j * 16 + h2 * 8);
  // drain qf BEFORE any slot DMA: ledger below contains only slot DMAs
  asm volatile("s_waitcnt vmcnt(0)" ::: "memory");

  ISSUE_SLOT(0) ISSUE_SLOT(1) ISSUE_SLOT(2)  // outstanding: 6

  f32x16 o0 = {}, o1 = {};
  float m_run = -1e30f, lsum = 0.f;

#define AITER(KT, NW)                                                             \
  {                                                                               \
    asm volatile("s_waitcnt vmcnt(" NW ")" ::: "memory");                         \
    __builtin_amdgcn_sched_barrier(0);                                            \
    asm volatile("s_barrier" ::: "memory");                                       \
    if ((KT) + 3 < 16) ISSUE_SLOT((KT) + 3)                                       \
    char* sl = ringB + ((KT)&3) * 8192;                                           \
    half8_t kf0 = *(const half8_t*)(sl + q32 * 128 + kof0);                       \
    half8_t kf1 = *(const half8_t*)(sl + q32 * 128 + kof1);                       \
    half8_t kf2 = *(const half8_t*)(sl + q32 * 128 + kof2);                       \
    half8_t kf3 = *(const half8_t*)(sl + q32 * 128 + kof3);                       \
    __builtin_amdgcn_s_setprio(1);                                                \
    f32x16 s = {};                                                                \
    s = __builtin_amdgcn_mfma_f32_32x32x16_f16(kf0, qf[0], s, 0, 0, 0);           \
    s = __builtin_amdgcn_mfma_f32_32x32x16_f16(kf1, qf[1], s, 0, 0, 0);           \
    s = __builtin_amdgcn_mfma_f32_32x32x16_f16(kf2, qf[2], s, 0, 0, 0);           \
    s = __builtin_amdgcn_mfma_f32_32x32x16_f16(kf3, qf[3], s, 0, 0, 0);           \
    __builtin_amdgcn_s_setprio(0);                                                \
    float ma = fmaxf(fmaxf(s[0], s[1]), s[2]);                                    \
    float mb = fmaxf(fmaxf(s[3], s[4]), s[5]);                                    \
    float mc = fmaxf(fmaxf(s[6], s[7]), s[8]);                                    \
    float md = fmaxf(fmaxf(s[9], s[10]), s[11]);                                  \
    float me = fmaxf(fmaxf(s[12], s[13]), s[14]);                                 \
    float mf_ = fmaxf(fmaxf(ma, mb), mc);                                         \
    float mg = fmaxf(fmaxf(md, me), s[15]);                                       \
    float tmax = fmaxf(mf_, mg);                                                  \
    tmax = fmaxf(tmax, __shfl_xor(tmax, 32));                                     \
    if (!__all(tmax <= m_run + 11.5f)) {                                          \
      float mNew = fmaxf(m_run, tmax);                                            \
      float sc = fexp2(m_run - mNew);                                             \
      lsum *= sc;                                                                 \
      _Pragma("unroll") for (int r = 0; r < 16; ++r) { o0[r] *= sc; o1[r] *= sc; }\
      m_run = mNew;                                                               \
    }                                                                             \
    half8_t pf0, pf1;                                                             \
    float tsum = 0.f;                                                             \
    _Pragma("unroll") for (int e = 0; e < 4; ++e) {                               \
      float a0 = fexp2(s[2 * e] - m_run), a1 = fexp2(s[2 * e + 1] - m_run);       \
      tsum += a0 + a1;                                                            \
      ((half2_t*)&pf0)[e] =                                                       \
          __builtin_bit_cast(half2_t, __builtin_amdgcn_cvt_pkrtz(a0, a1));        \
    }                                                                             \
    _Pragma("unroll") for (int e = 0; e < 4; ++e) {                               \
      float a0 = fexp2(s[8 + 2 * e] - m_run), a1 = fexp2(s[9 + 2 * e] - m_run);   \
      tsum += a0 + a1;                                                            \
      ((half2_t*)&pf1)[e] =                                                       \
          __builtin_bit_cast(half2_t, __builtin_amdgcn_cvt_pkrtz(a0, a1));        \
    }                                                                             \
    tsum += __shfl_xor(tsum, 32);                                                 \
    lsum += tsum;                                                                 \
    half8_t vf0 = *(const half8_t*)(sl + voff);                                   \
    half8_t vf1 = *(const half8_t*)(sl + voff + 512);                             \
    half8_t vf2 = *(const half8_t*)(sl + voff + 2048);                            \
    half8_t vf3 = *(const half8_t*)(sl + voff + 2560);                            \
    __builtin_amdgcn_s_setprio(1);                                                \
    o0 = __builtin_amdgcn_mfma_f32_32x32x16_f16(vf0, pf0, o0, 0, 0, 0);           \
    o1 = __builtin_amdgcn_mfma_f32_32x32x16_f16(vf1, pf0, o1, 0, 0, 0);           \
    o0 = __builtin_amdgcn_mfma_f32_32x32x16_f16(vf2, pf1, o0, 0, 0, 0);           \
    o1 = __builtin_amdgcn_mfma_f32_32x32x16_f16(vf3, pf1, o1, 0, 0, 0);           \
    __builtin_amdgcn_s_setprio(0);                                                \
  }

  // steady: outstanding 6 (slots KT..KT+2) -> vmcnt(4) drains slot KT; tail 4->2->0
  AITER(0, "4")  AITER(1, "4")  AITER(2, "4")  AITER(3, "4")
  AITER(4, "4")  AITER(5, "4")  AITER(6, "4")  AITER(7, "4")
  AITER(8, "4")  AITER(9, "4")  AITER(10, "4") AITER(11, "4")
  AITER(12, "4") AITER(13, "4") AITER(14, "2") AITER(15, "0")

  const float inv = 1.0f / lsum;
#pragma unroll
  for (int rq = 0; rq < 4; ++rq) {
    half4_t v0, v1;
#pragma unroll
    for (int i = 0; i < 4; ++i) {
      v0[i] = (_Float16)(o0[rq * 4 + i] * inv);
      v1[i] = (_Float16)(o1[rq * 4 + i] * inv);
    }
    *(half4_t*)(Qp + (size_t)qrow * 64 + 8 * rq + 4 * h2) = v0;
    *(half4_t*)(Qp + (size_t)qrow * 64 + 32 + 8 * rq + 4 * h2) = v1;
  }
}

// ---------------- GEMM2: out = attn_out @ Wproj + b, k-prefetched fragments ----------------
__global__ __launch_bounds__(256) void gemm2_proj(
    const _Float16* __restrict__ qkv,
    const _Float16* __restrict__ wpT,
    const float* __restrict__ bias,
    float* __restrict__ out) {
  const int tid = threadIdx.x, l = tid & 63;
  const int wid = tid >> 6, wr = wid >> 1, wc = wid & 1;
  const int lr = l & 15, lk8 = (l >> 4) * 8;
  const int m0 = blockIdx.x * 128, n0 = blockIdx.y * 128;
  size_t aBase[4];
#pragma unroll
  for (int mt = 0; mt < 4; ++mt) {
    int row = m0 + wr * 64 + mt * 16 + lr;
    int wL = row >> 9, n = row & 511;
    aBase[mt] = ((size_t)(wL * 24) << 15) + (size_t)n * 64 + lk8;
  }
  size_t bBase[4];
#pragma unroll
  for (int nt = 0; nt < 4; ++nt)
    bBase[nt] = (size_t)(n0 + wc * 64 + nt * 16 + lr) * 512 + lk8;

  half8_t a[4], b[4];
#pragma unroll
  for (int mt = 0; mt < 4; ++mt) a[mt] = *(const half8_t*)(qkv + aBase[mt]);
#pragma unroll
  for (int nt = 0; nt < 4; ++nt) b[nt] = *(const half8_t*)(wpT + bBase[nt]);

  f32x4 acc[4][4] = {};
#pragma unroll 2
  for (int ks = 0; ks < 16; ++ks) {
    half8_t an[4], bn[4];
    if (ks < 15) {
      const size_t aoff = (size_t)((ks + 1) >> 1) * 32768 + (size_t)((ks + 1) & 1) * 32;
#pragma unroll
      for (int mt = 0; mt < 4; ++mt) an[mt] = *(const half8_t*)(qkv + aBase[mt] + aoff);
#pragma unroll
      for (int nt = 0; nt < 4; ++nt) bn[nt] = *(const half8_t*)(wpT + bBase[nt] + (ks + 1) * 32);
    }
#pragma unroll
    for (int mt = 0; mt < 4; ++mt)
#pragma unroll
      for (int nt = 0; nt < 4; ++nt)
        acc[mt][nt] = __builtin_amdgcn_mfma_f32_16x16x32_f16(a[mt], b[nt], acc[mt][nt], 0, 0, 0);
#pragma unroll
    for (int i = 0; i < 4; ++i) { a[i] = an[i]; b[i] = bn[i]; }
  }
#pragma unroll
  for (int nt = 0; nt < 4; ++nt) {
    int col = n0 + wc * 64 + nt * 16 + lr;
    float bv = bias[col];
#pragma unroll
    for (int mt = 0; mt < 4; ++mt) {
      int row = m0 + wr * 64 + mt * 16 + ((l >> 4) << 2);
#pragma unroll
      for (int r = 0; r < 4; ++r)
        out[(size_t)(row + r) * 512 + col] = acc[mt][nt][r] + bv;
    }
  }
}

extern "C" void kernel_launch(void* const* d_in, const int* in_sizes, int n_in,
                              void* d_out, int out_size, void* d_ws, size_t ws_size,
                              hipStream_t stream) {
  const float* x = (const float*)d_in[0];
  const float* wqkv = (const float*)d_in[1];
  const float* bqkv = (const float*)d_in[2];
  const float* wproj = (const float*)d_in[3];
  const float* bproj = (const float*)d_in[4];
  float* out = (float*)d_out;

  _Float16* wqkvT = (_Float16*)d_ws;
  _Float16* wprojT = wqkvT + (size_t)TC * CDIM;
  _Float16* chunkws = wprojT + (size_t)CDIM * CDIM;
  const size_t fixed = ((size_t)TC * CDIM + (size_t)CDIM * CDIM) * sizeof(_Float16);
  const size_t perwin = ((size_t)NTOK * CDIM + (size_t)24 * 32768) * sizeof(_Float16);
  int nw = 64;
  while (nw > 1 && fixed + (size_t)nw * perwin > ws_size) nw >>= 1;

  prep_weights<<<dim3(256), 256, 0, stream>>>(wqkv, wproj, wqkvT, wprojT);
  for (int wbase = 0; wbase < NWIN; wbase += nw) {
    const float* xc = x + (size_t)wbase * NTOK * CDIM;
    float* oc = out + (size_t)wbase * NTOK * CDIM;
    _Float16* x16 = chunkws;
    _Float16* qkvws = chunkws + (size_t)nw * NTOK * CDIM;
    const int n8 = nw * NTOK * CDIM / 8;
    cvt_x<<<dim3((n8 + 255) / 256), 256, 0, stream>>>(xc, x16, n8);
    gemm1_qkv<<<dim3(nw * 4, 12), 256, 0, stream>>>(x16, wqkvT, bqkv, qkvws);
    attn_win<<<dim3(nw * 8, 4), 256, 0, stream>>>(qkvws);
    gemm2_proj<<<dim3(nw * 4, 4), 256, 0, stream>>>(qkvws, wprojT, bproj, oc);
  }
}

// Round 11
// 222.406 us; speedup vs baseline: 1.1774x; 1.0503x over previous
//
#include <hip/hip_runtime.h>
#include <hip/hip_bf16.h>

typedef _Float16 half8_t __attribute__((ext_vector_type(8)));
typedef _Float16 half4_t __attribute__((ext_vector_type(4)));
typedef _Float16 half2_t __attribute__((ext_vector_type(2)));
typedef float    f32x4   __attribute__((ext_vector_type(4)));
typedef float    f32x16  __attribute__((ext_vector_type(16)));

#define CDIM 512
#define NHEAD 8
#define HD 64
#define NTOK 512
#define NWIN 64
#define TC 1536  // 3*C

// raw v_exp_f32 (2^x); softmax inputs <= 11.5, large-negative underflows to 0.
__device__ __forceinline__ float fexp2(float x) {
  float r;
  asm("v_exp_f32 %0, %1" : "=v"(r) : "v"(x));
  return r;
}

// global->LDS direct DMA, 16B per lane, wave-uniform LDS base (m97 pattern)
#define GLL16(g, l)                                                        \
  __builtin_amdgcn_global_load_lds((const __attribute__((address_space(1))) void*)(g), \
                                   (__attribute__((address_space(3))) void*)(l), 16, 0, 0)

// ws panel layout: per (local window w): 24 panels of 32768 halfs (65536 B)
//   panel (w*24 + 0*8 + h): Q*log2e [n][d]  (later overwritten by attention output [n][d])
//   panel (w*24 + 1*8 + h): K  [n][d]
//   panel (w*24 + 2*8 + h): V key-permuted: [kg(32)][hh(2)][d(64)][e(8)]
//     key n -> kg=n>>4, hh=(n>>2)&1, e=(n&3)+4*((n>>3)&1)

// ---------------- x fp32 -> fp16 ----------------
__global__ __launch_bounds__(256) void cvt_x(const float* __restrict__ x,
                                             _Float16* __restrict__ x16, int n8) {
  int i = blockIdx.x * 256 + threadIdx.x;
  if (i < n8) {
    float4 v0 = *(const float4*)(x + (size_t)i * 8);
    float4 v1 = *(const float4*)(x + (size_t)i * 8 + 4);
    half8_t h = {(_Float16)v0.x, (_Float16)v0.y, (_Float16)v0.z, (_Float16)v0.w,
                 (_Float16)v1.x, (_Float16)v1.y, (_Float16)v1.z, (_Float16)v1.w};
    *(half8_t*)(x16 + (size_t)i * 8) = h;
  }
}

// ---------------- prep: fp32 -> fp16 transposes via LDS tiles ----------------
__global__ __launch_bounds__(256) void prep_weights(
    const float* __restrict__ wqkv, const float* __restrict__ wproj,
    _Float16* __restrict__ wqkvT, _Float16* __restrict__ wprojT) {
  __shared__ _Float16 T[64 * 65];
  int b = blockIdx.x;
  const float* src; _Float16* dst; int Cc, r0, c0;
  if (b < 192) {
    src = wqkv; dst = wqkvT; Cc = 1536;
    c0 = (b % 24) * 64; r0 = (b / 24) * 64;
  } else {
    b -= 192; src = wproj; dst = wprojT; Cc = 512;
    c0 = (b & 7) * 64; r0 = (b >> 3) * 64;
  }
  const int t = threadIdx.x;
#pragma unroll
  for (int i = 0; i < 16; ++i) {
    int idx = i * 256 + t, rr = idx >> 6, cc = idx & 63;
    T[rr * 65 + cc] = (_Float16)src[(size_t)(r0 + rr) * Cc + c0 + cc];
  }
  __syncthreads();
#pragma unroll
  for (int i = 0; i < 2; ++i) {
    int idx = i * 256 + t, ol = idx >> 3, c8 = idx & 7;
    half8_t vv;
#pragma unroll
    for (int e = 0; e < 8; ++e) vv[e] = T[(c8 * 8 + e) * 65 + ol];
    *(half8_t*)(dst + (size_t)(c0 + ol) * 512 + r0 + c8 * 8) = vv;
  }
}

// ---------------- GEMM1 v3: global_load_lds both operands, dbuf, 1 barrier/K-step ----------------
__global__ __launch_bounds__(256) void gemm1_qkv(
    const _Float16* __restrict__ x16,
    const _Float16* __restrict__ wT,
    const float* __restrict__ bias,
    _Float16* __restrict__ qkv) {
  __shared__ __align__(16) _Float16 smem[4 * 128 * 64];
  char* base = (char*)smem;
  const int tid = threadIdx.x;
  const int l = tid & 63;
  const int wid = tid >> 6;
  const int wr = wid >> 1, wc = wid & 1;
  const int lr = l & 15, g = l >> 4;
  const int swzf = (lr & 7) << 4;
  const int m0 = blockIdx.x * 128;
  const int cb = blockIdx.y * 128;
  const int j = cb >> 9;

  const int srow = l >> 3;
  const int scol = 16 * ((l & 7) ^ srow);
  const size_t aRowB = (size_t)(m0 + srow) * 1024 + scol;
  const size_t bRowB = (size_t)(cb + srow) * 1024 + scol;

#define STAGE_G1(buf, k0)                                                         \
  {                                                                               \
    char* Ad = base + (buf)*16384 + wid * 4096;                                   \
    char* Bd = base + 32768 + (buf)*16384 + wid * 4096;                           \
    _Pragma("unroll") for (int i = 0; i < 4; ++i) {                               \
      int chunk = wid * 4 + i;                                                    \
      GLL16((const char*)x16 + aRowB + (size_t)chunk * 8192 + (k0)*2, Ad + i * 1024); \
      GLL16((const char*)wT + bRowB + (size_t)chunk * 8192 + (k0)*2, Bd + i * 1024);  \
    }                                                                             \
  }

  STAGE_G1(0, 0);
  __syncthreads();

  f32x4 acc[4][4] = {};
  for (int ks = 0; ks < 8; ++ks) {
    const int cur = ks & 1;
    if (ks < 7) STAGE_G1(cur ^ 1, (ks + 1) * 64);
    char* AsB = base + cur * 16384;
    char* BsB = base + 32768 + cur * 16384;
#pragma unroll
    for (int kk = 0; kk < 2; ++kk) {
      half8_t a[4], b[4];
#pragma unroll
      for (int mt = 0; mt < 4; ++mt) {
        int row = wr * 64 + mt * 16 + lr;
        a[mt] = *(const half8_t*)(AsB + row * 128 + ((kk * 64 + g * 16) ^ swzf));
      }
#pragma unroll
      for (int nt = 0; nt < 4; ++nt) {
        int row = wc * 64 + nt * 16 + lr;
        b[nt] = *(const half8_t*)(BsB + row * 128 + ((kk * 64 + g * 16) ^ swzf));
      }
#pragma unroll
      for (int mt = 0; mt < 4; ++mt)
#pragma unroll
        for (int nt = 0; nt < 4; ++nt)
          acc[mt][nt] = __builtin_amdgcn_mfma_f32_16x16x32_f16(a[mt], b[nt], acc[mt][nt], 0, 0, 0);
    }
    __syncthreads();
  }

  if (j == 2) {  // V: key-permuted panels, 8B stores
#pragma unroll
    for (int nt = 0; nt < 4; ++nt) {
      const int ch = cb + wc * 64 + nt * 16 + lr;
      const int h = (ch >> 6) & 7, d = ch & 63;
      const float bvs = bias[ch];
#pragma unroll
      for (int mt = 0; mt < 4; ++mt) {
        const int row = m0 + wr * 64 + mt * 16 + g * 4;
        const int wL = row >> 9, n = row & 511;
        _Float16* panel = qkv + ((size_t)(wL * 24 + 16 + h) << 15);
        const int kg = n >> 4, hh = (n >> 2) & 1, e4 = (n & 8) >> 1;
        half4_t pk = {(_Float16)(acc[mt][nt][0] + bvs), (_Float16)(acc[mt][nt][1] + bvs),
                      (_Float16)(acc[mt][nt][2] + bvs), (_Float16)(acc[mt][nt][3] + bvs)};
        *(half4_t*)(panel + ((size_t)(kg * 2 + hh) * 64 + d) * 8 + e4) = pk;
      }
    }
  } else {  // Q/K: acc -> swizzled LDS C-tile -> coalesced 16B stores
    const float scl = (j == 0) ? 1.44269504f : 1.0f;
    char* CB = base;
#pragma unroll
    for (int nt = 0; nt < 4; ++nt) {
      const int chl = wc * 64 + nt * 16 + lr;
      const float bvs = bias[cb + chl];
#pragma unroll
      for (int mt = 0; mt < 4; ++mt) {
#pragma unroll
        for (int r = 0; r < 4; ++r) {
          int nl = wr * 64 + mt * 16 + g * 4 + r;
          *(_Float16*)(CB + nl * 256 + ((chl * 2) ^ ((nl & 7) << 5))) =
              (_Float16)((acc[mt][nt][r] + bvs) * scl);
        }
      }
    }
    __syncthreads();
#pragma unroll
    for (int i = 0; i < 8; ++i) {
      int idx = i * 256 + tid, nl = idx >> 4, c8 = idx & 15;
      half8_t vv = *(const half8_t*)(CB + nl * 256 + ((c8 * 16) ^ ((nl & 7) << 5)));
      int chg = cb + c8 * 8;
      int h = (chg >> 6) & 7, d = chg & 63;
      int ng = m0 + nl, wL = ng >> 9, nn = ng & 511;
      _Float16* panel = qkv + ((size_t)(wL * 24 + j * 8 + h) << 15);
      *(half8_t*)(panel + (size_t)nn * 64 + d) = vv;
    }
  }
}

// ---------------- attention v7: 8-wave blocks, LDS K/V ring, v6b ledger ----------------
// grid = dim3(nw*8, 2). Block = 8 waves on one (w,h) half (256 q-rows); ring 4 x 8KB
//   slot: [K 4KB swizzled (pre-swz source / swz read pair)] [V 4KB linear].
// Staging: waves 0-3 stage K chunk wid; waves 4-7 stage V chunk wid-4. 1 DMA/slot/wave.
// Ledger: qf drained up-front. Per iter: vmcnt(N) -> sched_barrier -> s_barrier ->
// issue slot KT+3 (overwrites KT-1, whose reads completed before this barrier) -> reads.
__global__ __launch_bounds__(512) void attn_win(_Float16* __restrict__ qkv) {
  __shared__ __align__(16) char ring[4 * 8192];
  char* ringB = ring;
  const int tid = threadIdx.x;
  const int l = tid & 63;
  const int wid = tid >> 6;   // 0..7
  const int q32 = l & 31;
  const int h2 = l >> 5;
  const int wh = blockIdx.x;
  const int qc = blockIdx.y;  // 0..1
  const int h = wh & 7;
  const int w = wh >> 3;
  _Float16* Qp = qkv + ((size_t)(w * 24 + h) << 15);
  const _Float16* Kp = qkv + ((size_t)(w * 24 + 8 + h) << 15);
  const _Float16* Vp = qkv + ((size_t)(w * 24 + 16 + h) << 15);
  const int qrow = qc * 256 + wid * 32 + q32;

  // K stage source pre-swizzle (write side of rule-21 pair)
  const size_t kSrc = (size_t)(l >> 3) * 128 + (size_t)((l & 7) ^ (l >> 3)) * 16;
  // K fragment read offsets (read side)
  const int kof0 = ((0 * 2 + h2) ^ (q32 & 7)) << 4;
  const int kof1 = ((1 * 2 + h2) ^ (q32 & 7)) << 4;
  const int kof2 = ((2 * 2 + h2) ^ (q32 & 7)) << 4;
  const int kof3 = ((3 * 2 + h2) ^ (q32 & 7)) << 4;
  const int voff = 4096 + h2 * 1024 + q32 * 16;

  // 1 DMA per slot per wave.
#define ISSUE_SLOT(KT)                                                            \
  {                                                                               \
    char* sb = ringB + ((KT)&3) * 8192;                                           \
    if (wid < 4) {                                                                \
      GLL16((const char*)Kp + (size_t)(KT)*4096 + (size_t)wid * 1024 + kSrc,      \
            sb + wid * 1024);                                                     \
    } else {                                                                      \
      GLL16((const char*)Vp + (size_t)(KT)*4096 + (size_t)(wid - 4) * 1024 + l * 16, \
            sb + 4096 + (wid - 4) * 1024);                                        \
    }                                                                             \
  }

  half8_t qf[4];  // Q (pre-scaled by log2e) B-frags
#pragma unroll
  for (int j = 0; j < 4; ++j)
    qf[j] = *(const half8_t*)(Qp + (size_t)qrow * 64 + j * 16 + h2 * 8);
  // drain qf BEFORE any slot DMA: ledger below contains only slot DMAs
  asm volatile("s_waitcnt vmcnt(0)" ::: "memory");

  ISSUE_SLOT(0) ISSUE_SLOT(1) ISSUE_SLOT(2)  // outstanding: 3

  f32x16 o0 = {}, o1 = {};
  float m_run = -1e30f, lsum = 0.f;

#define AITER(KT, NW)                                                             \
  {                                                                               \
    asm volatile("s_waitcnt vmcnt(" NW ")" ::: "memory");                         \
    __builtin_amdgcn_sched_barrier(0);                                            \
    asm volatile("s_barrier" ::: "memory");                                       \
    if ((KT) + 3 < 16) ISSUE_SLOT((KT) + 3)                                       \
    char* sl = ringB + ((KT)&3) * 8192;                                           \
    half8_t kf0 = *(const half8_t*)(sl + q32 * 128 + kof0);                       \
    half8_t kf1 = *(const half8_t*)(sl + q32 * 128 + kof1);                       \
    half8_t kf2 = *(const half8_t*)(sl + q32 * 128 + kof2);                       \
    half8_t kf3 = *(const half8_t*)(sl + q32 * 128 + kof3);                       \
    __builtin_amdgcn_s_setprio(1);                                                \
    f32x16 s = {};                                                                \
    s = __builtin_amdgcn_mfma_f32_32x32x16_f16(kf0, qf[0], s, 0, 0, 0);           \
    s = __builtin_amdgcn_mfma_f32_32x32x16_f16(kf1, qf[1], s, 0, 0, 0);           \
    s = __builtin_amdgcn_mfma_f32_32x32x16_f16(kf2, qf[2], s, 0, 0, 0);           \
    s = __builtin_amdgcn_mfma_f32_32x32x16_f16(kf3, qf[3], s, 0, 0, 0);           \
    __builtin_amdgcn_s_setprio(0);                                                \
    float ma = fmaxf(fmaxf(s[0], s[1]), s[2]);                                    \
    float mb = fmaxf(fmaxf(s[3], s[4]), s[5]);                                    \
    float mc = fmaxf(fmaxf(s[6], s[7]), s[8]);                                    \
    float md = fmaxf(fmaxf(s[9], s[10]), s[11]);                                  \
    float me = fmaxf(fmaxf(s[12], s[13]), s[14]);                                 \
    float mf_ = fmaxf(fmaxf(ma, mb), mc);                                         \
    float mg = fmaxf(fmaxf(md, me), s[15]);                                       \
    float tmax = fmaxf(mf_, mg);                                                  \
    tmax = fmaxf(tmax, __shfl_xor(tmax, 32));                                     \
    if (!__all(tmax <= m_run + 11.5f)) {                                          \
      float mNew = fmaxf(m_run, tmax);                                            \
      float sc = fexp2(m_run - mNew);                                             \
      lsum *= sc;                                                                 \
      _Pragma("unroll") for (int r = 0; r < 16; ++r) { o0[r] *= sc; o1[r] *= sc; }\
      m_run = mNew;                                                               \
    }                                                                             \
    half8_t pf0, pf1;                                                             \
    float tsum = 0.f;                                                             \
    _Pragma("unroll") for (int e = 0; e < 4; ++e) {                               \
      float a0 = fexp2(s[2 * e] - m_run), a1 = fexp2(s[2 * e + 1] - m_run);       \
      tsum += a0 + a1;                                                            \
      ((half2_t*)&pf0)[e] =                                                       \
          __builtin_bit_cast(half2_t, __builtin_amdgcn_cvt_pkrtz(a0, a1));        \
    }                                                                             \
    _Pragma("unroll") for (int e = 0; e < 4; ++e) {                               \
      float a0 = fexp2(s[8 + 2 * e] - m_run), a1 = fexp2(s[9 + 2 * e] - m_run);   \
      tsum += a0 + a1;                                                            \
      ((half2_t*)&pf1)[e] =                                                       \
          __builtin_bit_cast(half2_t, __builtin_amdgcn_cvt_pkrtz(a0, a1));        \
    }                                                                             \
    tsum += __shfl_xor(tsum, 32);                                                 \
    lsum += tsum;                                                                 \
    half8_t vf0 = *(const half8_t*)(sl + voff);                                   \
    half8_t vf1 = *(const half8_t*)(sl + voff + 512);                             \
    half8_t vf2 = *(const half8_t*)(sl + voff + 2048);                            \
    half8_t vf3 = *(const half8_t*)(sl + voff + 2560);                            \
    __builtin_amdgcn_s_setprio(1);                                                \
    o0 = __builtin_amdgcn_mfma_f32_32x32x16_f16(vf0, pf0, o0, 0, 0, 0);           \
    o1 = __builtin_amdgcn_mfma_f32_32x32x16_f16(vf1, pf0, o1, 0, 0, 0);           \
    o0 = __builtin_amdgcn_mfma_f32_32x32x16_f16(vf2, pf1, o0, 0, 0, 0);           \
    o1 = __builtin_amdgcn_mfma_f32_32x32x16_f16(vf3, pf1, o1, 0, 0, 0);           \
    __builtin_amdgcn_s_setprio(0);                                                \
  }

  // steady: outstanding 3 (slots KT..KT+2) -> vmcnt(2) drains slot KT; tail 1,0
  AITER(0, "2")  AITER(1, "2")  AITER(2, "2")  AITER(3, "2")
  AITER(4, "2")  AITER(5, "2")  AITER(6, "2")  AITER(7, "2")
  AITER(8, "2")  AITER(9, "2")  AITER(10, "2") AITER(11, "2")
  AITER(12, "2") AITER(13, "2") AITER(14, "1") AITER(15, "0")

  const float inv = 1.0f / lsum;
#pragma unroll
  for (int rq = 0; rq < 4; ++rq) {
    half4_t v0, v1;
#pragma unroll
    for (int i = 0; i < 4; ++i) {
      v0[i] = (_Float16)(o0[rq * 4 + i] * inv);
      v1[i] = (_Float16)(o1[rq * 4 + i] * inv);
    }
    *(half4_t*)(Qp + (size_t)qrow * 64 + 8 * rq + 4 * h2) = v0;
    *(half4_t*)(Qp + (size_t)qrow * 64 + 32 + 8 * rq + 4 * h2) = v1;
  }
}

// ---------------- GEMM2: out = attn_out @ Wproj + b, k-prefetched fragments ----------------
__global__ __launch_bounds__(256) void gemm2_proj(
    const _Float16* __restrict__ qkv,
    const _Float16* __restrict__ wpT,
    const float* __restrict__ bias,
    float* __restrict__ out) {
  const int tid = threadIdx.x, l = tid & 63;
  const int wid = tid >> 6, wr = wid >> 1, wc = wid & 1;
  const int lr = l & 15, lk8 = (l >> 4) * 8;
  const int m0 = blockIdx.x * 128, n0 = blockIdx.y * 128;
  size_t aBase[4];
#pragma unroll
  for (int mt = 0; mt < 4; ++mt) {
    int row = m0 + wr * 64 + mt * 16 + lr;
    int wL = row >> 9, n = row & 511;
    aBase[mt] = ((size_t)(wL * 24) << 15) + (size_t)n * 64 + lk8;
  }
  size_t bBase[4];
#pragma unroll
  for (int nt = 0; nt < 4; ++nt)
    bBase[nt] = (size_t)(n0 + wc * 64 + nt * 16 + lr) * 512 + lk8;

  half8_t a[4], b[4];
#pragma unroll
  for (int mt = 0; mt < 4; ++mt) a[mt] = *(const half8_t*)(qkv + aBase[mt]);
#pragma unroll
  for (int nt = 0; nt < 4; ++nt) b[nt] = *(const half8_t*)(wpT + bBase[nt]);

  f32x4 acc[4][4] = {};
#pragma unroll 2
  for (int ks = 0; ks < 16; ++ks) {
    half8_t an[4], bn[4];
    if (ks < 15) {
      const size_t aoff = (size_t)((ks + 1) >> 1) * 32768 + (size_t)((ks + 1) & 1) * 32;
#pragma unroll
      for (int mt = 0; mt < 4; ++mt) an[mt] = *(const half8_t*)(qkv + aBase[mt] + aoff);
#pragma unroll
      for (int nt = 0; nt < 4; ++nt) bn[nt] = *(const half8_t*)(wpT + bBase[nt] + (ks + 1) * 32);
    }
#pragma unroll
    for (int mt = 0; mt < 4; ++mt)
#pragma unroll
      for (int nt = 0; nt < 4; ++nt)
        acc[mt][nt] = __builtin_amdgcn_mfma_f32_16x16x32_f16(a[mt], b[nt], acc[mt][nt], 0, 0, 0);
#pragma unroll
    for (int i = 0; i < 4; ++i) { a[i] = an[i]; b[i] = bn[i]; }
  }
#pragma unroll
  for (int nt = 0; nt < 4; ++nt) {
    int col = n0 + wc * 64 + nt * 16 + lr;
    float bv = bias[col];
#pragma unroll
    for (int mt = 0; mt < 4; ++mt) {
      int row = m0 + wr * 64 + mt * 16 + ((l >> 4) << 2);
#pragma unroll
      for (int r = 0; r < 4; ++r)
        out[(size_t)(row + r) * 512 + col] = acc[mt][nt][r] + bv;
    }
  }
}

extern "C" void kernel_launch(void* const* d_in, const int* in_sizes, int n_in,
                              void* d_out, int out_size, void* d_ws, size_t ws_size,
                              hipStream_t stream) {
  const float* x = (const float*)d_in[0];
  const float* wqkv = (const float*)d_in[1];
  const float* bqkv = (const float*)d_in[2];
  const float* wproj = (const float*)d_in[3];
  const float* bproj = (const float*)d_in[4];
  float* out = (float*)d_out;

  _Float16* wqkvT = (_Float16*)d_ws;
  _Float16* wprojT = wqkvT + (size_t)TC * CDIM;
  _Float16* chunkws = wprojT + (size_t)CDIM * CDIM;
  const size_t fixed = ((size_t)TC * CDIM + (size_t)CDIM * CDIM) * sizeof(_Float16);
  const size_t perwin = ((size_t)NTOK * CDIM + (size_t)24 * 32768) * sizeof(_Float16);
  int nw = 64;
  while (nw > 1 && fixed + (size_t)nw * perwin > ws_size) nw >>= 1;

  prep_weights<<<dim3(256), 256, 0, stream>>>(wqkv, wproj, wqkvT, wprojT);
  for (int wbase = 0; wbase < NWIN; wbase += nw) {
    const float* xc = x + (size_t)wbase * NTOK * CDIM;
    float* oc = out + (size_t)wbase * NTOK * CDIM;
    _Float16* x16 = chunkws;
    _Float16* qkvws = chunkws + (size_t)nw * NTOK * CDIM;
    const int n8 = nw * NTOK * CDIM / 8;
    cvt_x<<<dim3((n8 + 255) / 256), 256, 0, stream>>>(xc, x16, n8);
    gemm1_qkv<<<dim3(nw * 4, 12), 256, 0, stream>>>(x16, wqkvT, bqkv, qkvws);
    attn_win<<<dim3(nw * 8, 2), 512, 0, stream>>>(qkvws);
    gemm2_proj<<<dim3(nw * 4, 4), 256, 0, stream>>>(qkvws, wprojT, bproj, oc);
  }
}

// Round 12
// 216.970 us; speedup vs baseline: 1.2069x; 1.0251x over previous
//
#include <hip/hip_runtime.h>
#include <hip/hip_bf16.h>

typedef _Float16 half8_t __attribute__((ext_vector_type(8)));
typedef _Float16 half4_t __attribute__((ext_vector_type(4)));
typedef _Float16 half2_t __attribute__((ext_vector_type(2)));
typedef float    f32x4   __attribute__((ext_vector_type(4)));
typedef float    f32x16  __attribute__((ext_vector_type(16)));

#define CDIM 512
#define NHEAD 8
#define HD 64
#define NTOK 512
#define NWIN 64
#define TC 1536  // 3*C

// raw v_exp_f32 (2^x); softmax inputs <= 11.5, large-negative underflows to 0.
__device__ __forceinline__ float fexp2(float x) {
  float r;
  asm("v_exp_f32 %0, %1" : "=v"(r) : "v"(x));
  return r;
}

// global->LDS direct DMA, 16B per lane, wave-uniform LDS base (m97 pattern)
#define GLL16(g, l)                                                        \
  __builtin_amdgcn_global_load_lds((const __attribute__((address_space(1))) void*)(g), \
                                   (__attribute__((address_space(3))) void*)(l), 16, 0, 0)

// ws panel layout: per (local window w): 24 panels of 32768 halfs (65536 B)
//   panel (w*24 + 0*8 + h): Q*log2e [n][d]  (later overwritten by attention output [n][d])
//   panel (w*24 + 1*8 + h): K  [n][d]
//   panel (w*24 + 2*8 + h): V key-permuted: [kg(32)][hh(2)][d(64)][e(8)]
//     key n -> kg=n>>4, hh=(n>>2)&1, e=(n&3)+4*((n>>3)&1)

// ---------------- x fp32 -> fp16 ----------------
__global__ __launch_bounds__(256) void cvt_x(const float* __restrict__ x,
                                             _Float16* __restrict__ x16, int n8) {
  int i = blockIdx.x * 256 + threadIdx.x;
  if (i < n8) {
    float4 v0 = *(const float4*)(x + (size_t)i * 8);
    float4 v1 = *(const float4*)(x + (size_t)i * 8 + 4);
    half8_t h = {(_Float16)v0.x, (_Float16)v0.y, (_Float16)v0.z, (_Float16)v0.w,
                 (_Float16)v1.x, (_Float16)v1.y, (_Float16)v1.z, (_Float16)v1.w};
    *(half8_t*)(x16 + (size_t)i * 8) = h;
  }
}

// ---------------- prep: fp32 -> fp16 transposes via LDS tiles ----------------
__global__ __launch_bounds__(256) void prep_weights(
    const float* __restrict__ wqkv, const float* __restrict__ wproj,
    _Float16* __restrict__ wqkvT, _Float16* __restrict__ wprojT) {
  __shared__ _Float16 T[64 * 65];
  int b = blockIdx.x;
  const float* src; _Float16* dst; int Cc, r0, c0;
  if (b < 192) {
    src = wqkv; dst = wqkvT; Cc = 1536;
    c0 = (b % 24) * 64; r0 = (b / 24) * 64;
  } else {
    b -= 192; src = wproj; dst = wprojT; Cc = 512;
    c0 = (b & 7) * 64; r0 = (b >> 3) * 64;
  }
  const int t = threadIdx.x;
#pragma unroll
  for (int i = 0; i < 16; ++i) {
    int idx = i * 256 + t, rr = idx >> 6, cc = idx & 63;
    T[rr * 65 + cc] = (_Float16)src[(size_t)(r0 + rr) * Cc + c0 + cc];
  }
  __syncthreads();
#pragma unroll
  for (int i = 0; i < 2; ++i) {
    int idx = i * 256 + t, ol = idx >> 3, c8 = idx & 7;
    half8_t vv;
#pragma unroll
    for (int e = 0; e < 8; ++e) vv[e] = T[(c8 * 8 + e) * 65 + ol];
    *(half8_t*)(dst + (size_t)(c0 + ol) * 512 + r0 + c8 * 8) = vv;
  }
}

// ---------------- GEMM1 v6: 256x256 tile, 8 waves, BK=32, ring-4, counted vmcnt ----------------
// grid = dim3(nw*2, 6); block 512. Slot = [A 256x32 fp16, 16KB][B 256x32 fp16, 16KB], ring of 4
// = 128KB. Swizzle pair: stage src chunk (l&3)^((l>>2)&3), frag read g^(lr&3) (rule #21).
// Ledger (mirrors attn v7): prologue slots 0,1,2 (12 DMAs/thread... 4/slot); per iter:
//   vmcnt(8) [drain slot ks; ks+1,ks+2 in flight] -> sched_barrier -> s_barrier ->
//   issue slot ks+3 (overwrites ks-1: its reads completed before this barrier) -> reads+MFMA.
__global__ __launch_bounds__(512, 2) void gemm1_qkv(
    const _Float16* __restrict__ x16,
    const _Float16* __restrict__ wT,
    const float* __restrict__ bias,
    _Float16* __restrict__ qkv) {
  __shared__ __align__(16) char ring[4 * 32768];  // 128KB; epilogue reuses as 256x256 C-tile
  char* ringB = ring;
  const int tid = threadIdx.x;
  const int l = tid & 63;
  const int wid = tid >> 6;            // 0..7
  const int wr = wid >> 2, wc = wid & 3;  // 2M x 4N waves; per-wave 128x64 output
  const int lr = l & 15, g = l >> 4;
  const int koff = ((g ^ (lr & 3)) << 4);  // frag-read swizzle within 64B rows
  const int m0 = blockIdx.x * 256;
  const int cb = blockIdx.y * 256;     // channel base: {0,256,512,768,1024,1280}
  const int j = cb >> 9;               // 0=Q 1=K 2=V (uniform per block)

  // stage source geometry: lane l covers row (wid*32 + i*16 + (l>>2)), chunk l&3 (swizzled)
  const int srow4 = l >> 2;
  const int schk = (l & 3) ^ (srow4 & 3);
  const size_t aSrc = (size_t)(m0 + wid * 32 + srow4) * 1024 + ((size_t)schk << 4);
  const size_t bSrc = (size_t)(cb + wid * 32 + srow4) * 1024 + ((size_t)schk << 4);

#define ISSUE_G1(KS)                                                              \
  {                                                                               \
    char* sa = ringB + ((KS)&3) * 32768;                                          \
    char* sb = sa + 16384;                                                        \
    _Pragma("unroll") for (int i = 0; i < 2; ++i) {                               \
      GLL16((const char*)x16 + aSrc + (size_t)i * 16384 + (size_t)(KS)*64,        \
            sa + wid * 2048 + i * 1024);                                          \
      GLL16((const char*)wT + bSrc + (size_t)i * 16384 + (size_t)(KS)*64,         \
            sb + wid * 2048 + i * 1024);                                          \
    }                                                                             \
  }

  ISSUE_G1(0) ISSUE_G1(1) ISSUE_G1(2)  // outstanding: 12 (4/slot/thread)

  f32x4 acc[8][4] = {};

#define GITER(KS, NW)                                                             \
  {                                                                               \
    asm volatile("s_waitcnt vmcnt(" NW ")" ::: "memory");                         \
    __builtin_amdgcn_sched_barrier(0);                                            \
    asm volatile("s_barrier" ::: "memory");                                       \
    if ((KS) + 3 < 16) ISSUE_G1((KS) + 3)                                         \
    char* sa = ringB + ((KS)&3) * 32768;                                          \
    char* sb = sa + 16384;                                                        \
    half8_t a[8], b[4];                                                           \
    _Pragma("unroll") for (int mt = 0; mt < 8; ++mt)                              \
        a[mt] = *(const half8_t*)(sa + (wr * 128 + mt * 16 + lr) * 64 + koff);    \
    _Pragma("unroll") for (int nt = 0; nt < 4; ++nt)                              \
        b[nt] = *(const half8_t*)(sb + (wc * 64 + nt * 16 + lr) * 64 + koff);     \
    __builtin_amdgcn_s_setprio(1);                                                \
    _Pragma("unroll") for (int mt = 0; mt < 8; ++mt)                              \
        _Pragma("unroll") for (int nt = 0; nt < 4; ++nt)                          \
            acc[mt][nt] =                                                         \
                __builtin_amdgcn_mfma_f32_16x16x32_f16(a[mt], b[nt], acc[mt][nt], 0, 0, 0); \
    __builtin_amdgcn_s_setprio(0);                                                \
  }

  // steady outstanding at vmcnt = 12 (slots KS..KS+2) -> vmcnt(8) drains slot KS; tail 4,0
  GITER(0, "8")  GITER(1, "8")  GITER(2, "8")  GITER(3, "8")
  GITER(4, "8")  GITER(5, "8")  GITER(6, "8")  GITER(7, "8")
  GITER(8, "8")  GITER(9, "8")  GITER(10, "8") GITER(11, "8")
  GITER(12, "8") GITER(13, "8") GITER(14, "4") GITER(15, "0")

  if (j == 2) {  // V: key-permuted panels, 8B stores (no LDS reuse needed)
#pragma unroll
    for (int nt = 0; nt < 4; ++nt) {
      const int ch = cb + wc * 64 + nt * 16 + lr;
      const int h = (ch >> 6) & 7, d = ch & 63;
      const float bvs = bias[ch];
#pragma unroll
      for (int mt = 0; mt < 8; ++mt) {
        const int row = m0 + wr * 128 + mt * 16 + g * 4;
        const int wL = row >> 9, n = row & 511;
        _Float16* panel = qkv + ((size_t)(wL * 24 + 16 + h) << 15);
        const int kg = n >> 4, hh = (n >> 2) & 1, e4 = (n & 8) >> 1;
        half4_t pk = {(_Float16)(acc[mt][nt][0] + bvs), (_Float16)(acc[mt][nt][1] + bvs),
                      (_Float16)(acc[mt][nt][2] + bvs), (_Float16)(acc[mt][nt][3] + bvs)};
        *(half4_t*)(panel + ((size_t)(kg * 2 + hh) * 64 + d) * 8 + e4) = pk;
      }
    }
  } else {  // Q/K: acc -> swizzled LDS C-tile (reuse ring) -> coalesced 16B stores
    __syncthreads();  // all slot reads done; safe to reuse ring (vmcnt already 0)
    const float scl = (j == 0) ? 1.44269504f : 1.0f;
    char* CB = ringB;
#pragma unroll
    for (int nt = 0; nt < 4; ++nt) {
      const int chl = wc * 64 + nt * 16 + lr;
      const float bvs = bias[cb + chl];
#pragma unroll
      for (int mt = 0; mt < 8; ++mt) {
#pragma unroll
        for (int r = 0; r < 4; ++r) {
          int nl = wr * 128 + mt * 16 + g * 4 + r;
          *(_Float16*)(CB + nl * 512 + ((chl * 2) ^ ((nl & 7) << 5))) =
              (_Float16)((acc[mt][nt][r] + bvs) * scl);
        }
      }
    }
    __syncthreads();
#pragma unroll
    for (int i = 0; i < 16; ++i) {
      int idx = i * 512 + tid, nl = idx >> 5, c8 = idx & 31;
      half8_t vv = *(const half8_t*)(CB + nl * 512 + ((c8 * 16) ^ ((nl & 7) << 5)));
      int chg = cb + c8 * 8;
      int h = (chg >> 6) & 7, d = chg & 63;
      int ng = m0 + nl, wL = ng >> 9, nn = ng & 511;
      _Float16* panel = qkv + ((size_t)(wL * 24 + j * 8 + h) << 15);
      *(half8_t*)(panel + (size_t)nn * 64 + d) = vv;
    }
  }
}

// ---------------- attention v7: 8-wave blocks, LDS K/V ring, counted vmcnt ----------------
// grid = dim3(nw*8, 2). Block = 8 waves on one (w,h) half (256 q-rows); ring 4 x 8KB.
__global__ __launch_bounds__(512) void attn_win(_Float16* __restrict__ qkv) {
  __shared__ __align__(16) char ring[4 * 8192];
  char* ringB = ring;
  const int tid = threadIdx.x;
  const int l = tid & 63;
  const int wid = tid >> 6;   // 0..7
  const int q32 = l & 31;
  const int h2 = l >> 5;
  const int wh = blockIdx.x;
  const int qc = blockIdx.y;  // 0..1
  const int h = wh & 7;
  const int w = wh >> 3;
  _Float16* Qp = qkv + ((size_t)(w * 24 + h) << 15);
  const _Float16* Kp = qkv + ((size_t)(w * 24 + 8 + h) << 15);
  const _Float16* Vp = qkv + ((size_t)(w * 24 + 16 + h) << 15);
  const int qrow = qc * 256 + wid * 32 + q32;

  const size_t kSrc = (size_t)(l >> 3) * 128 + (size_t)((l & 7) ^ (l >> 3)) * 16;
  const int kof0 = ((0 * 2 + h2) ^ (q32 & 7)) << 4;
  const int kof1 = ((1 * 2 + h2) ^ (q32 & 7)) << 4;
  const int kof2 = ((2 * 2 + h2) ^ (q32 & 7)) << 4;
  const int kof3 = ((3 * 2 + h2) ^ (q32 & 7)) << 4;
  const int voff = 4096 + h2 * 1024 + q32 * 16;

#define ISSUE_SLOT(KT)                                                            \
  {                                                                               \
    char* sb = ringB + ((KT)&3) * 8192;                                           \
    if (wid < 4) {                                                                \
      GLL16((const char*)Kp + (size_t)(KT)*4096 + (size_t)wid * 1024 + kSrc,      \
            sb + wid * 1024);                                                     \
    } else {                                                                      \
      GLL16((const char*)Vp + (size_t)(KT)*4096 + (size_t)(wid - 4) * 1024 + l * 16, \
            sb + 4096 + (wid - 4) * 1024);                                        \
    }                                                                             \
  }

  half8_t qf[4];
#pragma unroll
  for (int j = 0; j < 4; ++j)
    qf[j] = *(const half8_t*)(Qp + (size_t)qrow * 64 + j * 16 + h2 * 8);
  asm volatile("s_waitcnt vmcnt(0)" ::: "memory");

  ISSUE_SLOT(0) ISSUE_SLOT(1) ISSUE_SLOT(2)

  f32x16 o0 = {}, o1 = {};
  float m_run = -1e30f, lsum = 0.f;

#define AITER(KT, NW)                                                             \
  {                                                                               \
    asm volatile("s_waitcnt vmcnt(" NW ")" ::: "memory");                         \
    __builtin_amdgcn_sched_barrier(0);                                            \
    asm volatile("s_barrier" ::: "memory");                                       \
    if ((KT) + 3 < 16) ISSUE_SLOT((KT) + 3)                                       \
    char* sl = ringB + ((KT)&3) * 8192;                                           \
    half8_t kf0 = *(const half8_t*)(sl + q32 * 128 + kof0);                       \
    half8_t kf1 = *(const half8_t*)(sl + q32 * 128 + kof1);                       \
    half8_t kf2 = *(const half8_t*)(sl + q32 * 128 + kof2);                       \
    half8_t kf3 = *(const half8_t*)(sl + q32 * 128 + kof3);                       \
    __builtin_amdgcn_s_setprio(1);                                                \
    f32x16 s = {};                                                                \
    s = __builtin_amdgcn_mfma_f32_32x32x16_f16(kf0, qf[0], s, 0, 0, 0);           \
    s = __builtin_amdgcn_mfma_f32_32x32x16_f16(kf1, qf[1], s, 0, 0, 0);           \
    s = __builtin_amdgcn_mfma_f32_32x32x16_f16(kf2, qf[2], s, 0, 0, 0);           \
    s = __builtin_amdgcn_mfma_f32_32x32x16_f16(kf3, qf[3], s, 0, 0, 0);           \
    __builtin_amdgcn_s_setprio(0);                                                \
    float ma = fmaxf(fmaxf(s[0], s[1]), s[2]);                                    \
    float mb = fmaxf(fmaxf(s[3], s[4]), s[5]);                                    \
    float mc = fmaxf(fmaxf(s[6], s[7]), s[8]);                                    \
    float md = fmaxf(fmaxf(s[9], s[10]), s[11]);                                  \
    float me = fmaxf(fmaxf(s[12], s[13]), s[14]);                                 \
    float mf_ = fmaxf(fmaxf(ma, mb), mc);                                         \
    float mg = fmaxf(fmaxf(md, me), s[15]);                                       \
    float tmax = fmaxf(mf_, mg);                                                  \
    tmax = fmaxf(tmax, __shfl_xor(tmax, 32));                                     \
    if (!__all(tmax <= m_run + 11.5f)) {                                          \
      float mNew = fmaxf(m_run, tmax);                                            \
      float sc = fexp2(m_run - mNew);                                             \
      lsum *= sc;                                                                 \
      _Pragma("unroll") for (int r = 0; r < 16; ++r) { o0[r] *= sc; o1[r] *= sc; }\
      m_run = mNew;                                                               \
    }                                                                             \
    half8_t pf0, pf1;                                                             \
    float tsum = 0.f;                                                             \
    _Pragma("unroll") for (int e = 0; e < 4; ++e) {                               \
      float a0 = fexp2(s[2 * e] - m_run), a1 = fexp2(s[2 * e + 1] - m_run);       \
      tsum += a0 + a1;                                                            \
      ((half2_t*)&pf0)[e] =                                                       \
          __builtin_bit_cast(half2_t, __builtin_amdgcn_cvt_pkrtz(a0, a1));        \
    }                                                                             \
    _Pragma("unroll") for (int e = 0; e < 4; ++e) {                               \
      float a0 = fexp2(s[8 + 2 * e] - m_run), a1 = fexp2(s[9 + 2 * e] - m_run);   \
      tsum += a0 + a1;                                                            \
      ((half2_t*)&pf1)[e] =                                                       \
          __builtin_bit_cast(half2_t, __builtin_amdgcn_cvt_pkrtz(a0, a1));        \
    }                                                                             \
    tsum += __shfl_xor(tsum, 32);                                                 \
    lsum += tsum;                                                                 \
    half8_t vf0 = *(const half8_t*)(sl + voff);                                   \
    half8_t vf1 = *(const half8_t*)(sl + voff + 512);                             \
    half8_t vf2 = *(const half8_t*)(sl + voff + 2048);                            \
    half8_t vf3 = *(const half8_t*)(sl + voff + 2560);                            \
    __builtin_amdgcn_s_setprio(1);                                                \
    o0 = __builtin_amdgcn_mfma_f32_32x32x16_f16(vf0, pf0, o0, 0, 0, 0);           \
    o1 = __builtin_amdgcn_mfma_f32_32x32x16_f16(vf1, pf0, o1, 0, 0, 0);           \
    o0 = __builtin_amdgcn_mfma_f32_32x32x16_f16(vf2, pf1, o0, 0, 0, 0);           \
    o1 = __builtin_amdgcn_mfma_f32_32x32x16_f16(vf3, pf1, o1, 0, 0, 0);           \
    __builtin_amdgcn_s_setprio(0);                                                \
  }

  AITER(0, "2")  AITER(1, "2")  AITER(2, "2")  AITER(3, "2")
  AITER(4, "2")  AITER(5, "2")  AITER(6, "2")  AITER(7, "2")
  AITER(8, "2")  AITER(9, "2")  AITER(10, "2") AITER(11, "2")
  AITER(12, "2") AITER(13, "2") AITER(14, "1") AITER(15, "0")

  const float inv = 1.0f / lsum;
#pragma unroll
  for (int rq = 0; rq < 4; ++rq) {
    half4_t v0, v1;
#pragma unroll
    for (int i = 0; i < 4; ++i) {
      v0[i] = (_Float16)(o0[rq * 4 + i] * inv);
      v1[i] = (_Float16)(o1[rq * 4 + i] * inv);
    }
    *(half4_t*)(Qp + (size_t)qrow * 64 + 8 * rq + 4 * h2) = v0;
    *(half4_t*)(Qp + (size_t)qrow * 64 + 32 + 8 * rq + 4 * h2) = v1;
  }
}

// ---------------- GEMM2: out = attn_out @ Wproj + b, k-prefetched fragments ----------------
__global__ __launch_bounds__(256) void gemm2_proj(
    const _Float16* __restrict__ qkv,
    const _Float16* __restrict__ wpT,
    const float* __restrict__ bias,
    float* __restrict__ out) {
  const int tid = threadIdx.x, l = tid & 63;
  const int wid = tid >> 6, wr = wid >> 1, wc = wid & 1;
  const int lr = l & 15, lk8 = (l >> 4) * 8;
  const int m0 = blockIdx.x * 128, n0 = blockIdx.y * 128;
  size_t aBase[4];
#pragma unroll
  for (int mt = 0; mt < 4; ++mt) {
    int row = m0 + wr * 64 + mt * 16 + lr;
    int wL = row >> 9, n = row & 511;
    aBase[mt] = ((size_t)(wL * 24) << 15) + (size_t)n * 64 + lk8;
  }
  size_t bBase[4];
#pragma unroll
  for (int nt = 0; nt < 4; ++nt)
    bBase[nt] = (size_t)(n0 + wc * 64 + nt * 16 + lr) * 512 + lk8;

  half8_t a[4], b[4];
#pragma unroll
  for (int mt = 0; mt < 4; ++mt) a[mt] = *(const half8_t*)(qkv + aBase[mt]);
#pragma unroll
  for (int nt = 0; nt < 4; ++nt) b[nt] = *(const half8_t*)(wpT + bBase[nt]);

  f32x4 acc[4][4] = {};
#pragma unroll 2
  for (int ks = 0; ks < 16; ++ks) {
    half8_t an[4], bn[4];
    if (ks < 15) {
      const size_t aoff = (size_t)((ks + 1) >> 1) * 32768 + (size_t)((ks + 1) & 1) * 32;
#pragma unroll
      for (int mt = 0; mt < 4; ++mt) an[mt] = *(const half8_t*)(qkv + aBase[mt] + aoff);
#pragma unroll
      for (int nt = 0; nt < 4; ++nt) bn[nt] = *(const half8_t*)(wpT + bBase[nt] + (ks + 1) * 32);
    }
#pragma unroll
    for (int mt = 0; mt < 4; ++mt)
#pragma unroll
      for (int nt = 0; nt < 4; ++nt)
        acc[mt][nt] = __builtin_amdgcn_mfma_f32_16x16x32_f16(a[mt], b[nt], acc[mt][nt], 0, 0, 0);
#pragma unroll
    for (int i = 0; i < 4; ++i) { a[i] = an[i]; b[i] = bn[i]; }
  }
#pragma unroll
  for (int nt = 0; nt < 4; ++nt) {
    int col = n0 + wc * 64 + nt * 16 + lr;
    float bv = bias[col];
#pragma unroll
    for (int mt = 0; mt < 4; ++mt) {
      int row = m0 + wr * 64 + mt * 16 + ((l >> 4) << 2);
#pragma unroll
      for (int r = 0; r < 4; ++r)
        out[(size_t)(row + r) * 512 + col] = acc[mt][nt][r] + bv;
    }
  }
}

extern "C" void kernel_launch(void* const* d_in, const int* in_sizes, int n_in,
                              void* d_out, int out_size, void* d_ws, size_t ws_size,
                              hipStream_t stream) {
  const float* x = (const float*)d_in[0];
  const float* wqkv = (const float*)d_in[1];
  const float* bqkv = (const float*)d_in[2];
  const float* wproj = (const float*)d_in[3];
  const float* bproj = (const float*)d_in[4];
  float* out = (float*)d_out;

  _Float16* wqkvT = (_Float16*)d_ws;
  _Float16* wprojT = wqkvT + (size_t)TC * CDIM;
  _Float16* chunkws = wprojT + (size_t)CDIM * CDIM;
  const size_t fixed = ((size_t)TC * CDIM + (size_t)CDIM * CDIM) * sizeof(_Float16);
  const size_t perwin = ((size_t)NTOK * CDIM + (size_t)24 * 32768) * sizeof(_Float16);
  int nw = 64;
  while (nw > 1 && fixed + (size_t)nw * perwin > ws_size) nw >>= 1;

  prep_weights<<<dim3(256), 256, 0, stream>>>(wqkv, wproj, wqkvT, wprojT);
  for (int wbase = 0; wbase < NWIN; wbase += nw) {
    const float* xc = x + (size_t)wbase * NTOK * CDIM;
    float* oc = out + (size_t)wbase * NTOK * CDIM;
    _Float16* x16 = chunkws;
    _Float16* qkvws = chunkws + (size_t)nw * NTOK * CDIM;
    const int n8 = nw * NTOK * CDIM / 8;
    cvt_x<<<dim3((n8 + 255) / 256), 256, 0, stream>>>(xc, x16, n8);
    gemm1_qkv<<<dim3(nw * 2, 6), 512, 0, stream>>>(x16, wqkvT, bqkv, qkvws);
    attn_win<<<dim3(nw * 8, 2), 512, 0, stream>>>(qkvws);
    gemm2_proj<<<dim3(nw * 4, 4), 256, 0, stream>>>(qkvws, wprojT, bproj, oc);
  }
}

// Round 13
// 216.732 us; speedup vs baseline: 1.2083x; 1.0011x over previous
//
#include <hip/hip_runtime.h>
#include <hip/hip_bf16.h>

typedef _Float16 half8_t __attribute__((ext_vector_type(8)));
typedef _Float16 half4_t __attribute__((ext_vector_type(4)));
typedef _Float16 half2_t __attribute__((ext_vector_type(2)));
typedef float    f32x4   __attribute__((ext_vector_type(4)));
typedef float    f32x16  __attribute__((ext_vector_type(16)));

#define CDIM 512
#define NHEAD 8
#define HD 64
#define NTOK 512
#define NWIN 64
#define TC 1536  // 3*C

// raw v_exp_f32 (2^x); softmax inputs <= 11.5, large-negative underflows to 0.
__device__ __forceinline__ float fexp2(float x) {
  float r;
  asm("v_exp_f32 %0, %1" : "=v"(r) : "v"(x));
  return r;
}

// global->LDS direct DMA, 16B per lane, wave-uniform LDS base (m97 pattern)
#define GLL16(g, l)                                                        \
  __builtin_amdgcn_global_load_lds((const __attribute__((address_space(1))) void*)(g), \
                                   (__attribute__((address_space(3))) void*)(l), 16, 0, 0)

// ws panel layout: per (local window w): 24 panels of 32768 halfs (65536 B)
//   panel (w*24 + 0*8 + h): Q*log2e [n][d]  (later overwritten by attention output [n][d])
//   panel (w*24 + 1*8 + h): K  [n][d]
//   panel (w*24 + 2*8 + h): V key-permuted: [kg(32)][hh(2)][d(64)][e(8)]
//     key n -> kg=n>>4, hh=(n>>2)&1, e=(n&3)+4*((n>>3)&1)

// ---------------- x fp32 -> fp16 ----------------
__global__ __launch_bounds__(256) void cvt_x(const float* __restrict__ x,
                                             _Float16* __restrict__ x16, int n8) {
  int i = blockIdx.x * 256 + threadIdx.x;
  if (i < n8) {
    float4 v0 = *(const float4*)(x + (size_t)i * 8);
    float4 v1 = *(const float4*)(x + (size_t)i * 8 + 4);
    half8_t h = {(_Float16)v0.x, (_Float16)v0.y, (_Float16)v0.z, (_Float16)v0.w,
                 (_Float16)v1.x, (_Float16)v1.y, (_Float16)v1.z, (_Float16)v1.w};
    *(half8_t*)(x16 + (size_t)i * 8) = h;
  }
}

// ---------------- prep: fp32 -> fp16 transposes via LDS tiles ----------------
__global__ __launch_bounds__(256) void prep_weights(
    const float* __restrict__ wqkv, const float* __restrict__ wproj,
    _Float16* __restrict__ wqkvT, _Float16* __restrict__ wprojT) {
  __shared__ _Float16 T[64 * 65];
  int b = blockIdx.x;
  const float* src; _Float16* dst; int Cc, r0, c0;
  if (b < 192) {
    src = wqkv; dst = wqkvT; Cc = 1536;
    c0 = (b % 24) * 64; r0 = (b / 24) * 64;
  } else {
    b -= 192; src = wproj; dst = wprojT; Cc = 512;
    c0 = (b & 7) * 64; r0 = (b >> 3) * 64;
  }
  const int t = threadIdx.x;
#pragma unroll
  for (int i = 0; i < 16; ++i) {
    int idx = i * 256 + t, rr = idx >> 6, cc = idx & 63;
    T[rr * 65 + cc] = (_Float16)src[(size_t)(r0 + rr) * Cc + c0 + cc];
  }
  __syncthreads();
#pragma unroll
  for (int i = 0; i < 2; ++i) {
    int idx = i * 256 + t, ol = idx >> 3, c8 = idx & 7;
    half8_t vv;
#pragma unroll
    for (int e = 0; e < 8; ++e) vv[e] = T[(c8 * 8 + e) * 65 + ol];
    *(half8_t*)(dst + (size_t)(c0 + ol) * 512 + r0 + c8 * 8) = vv;
  }
}

// ---------------- GEMM1 v6b: 256x256 tile, 8 waves, BK=32, ring-4, counted vmcnt ----------------
// Swizzle pair FIXED for 64B rows (round-12 postmortem): store src chunk (l&3)^((srow4>>1)&3),
// frag read (g^((lr>>1)&3))<<4 -> per quarter-wave, 8 bank-groups covered exactly 2x (free).
__global__ __launch_bounds__(512, 2) void gemm1_qkv(
    const _Float16* __restrict__ x16,
    const _Float16* __restrict__ wT,
    const float* __restrict__ bias,
    _Float16* __restrict__ qkv) {
  __shared__ __align__(16) char ring[4 * 32768];  // 128KB; epilogue reuses as 256x256 C-tile
  char* ringB = ring;
  const int tid = threadIdx.x;
  const int l = tid & 63;
  const int wid = tid >> 6;            // 0..7
  const int wr = wid >> 2, wc = wid & 3;  // 2M x 4N waves; per-wave 128x64 output
  const int lr = l & 15, g = l >> 4;
  const int koff = ((g ^ ((lr >> 1) & 3)) << 4);  // frag-read swizzle (64B-row conflict-free)
  const int m0 = blockIdx.x * 256;
  const int cb = blockIdx.y * 256;     // channel base: {0,256,512,768,1024,1280}
  const int j = cb >> 9;               // 0=Q 1=K 2=V (uniform per block)

  // stage source geometry: lane l covers row (wid*32 + i*16 + (l>>2)), chunk (l&3) swizzled
  const int srow4 = l >> 2;
  const int schk = (l & 3) ^ ((srow4 >> 1) & 3);
  const size_t aSrc = (size_t)(m0 + wid * 32 + srow4) * 1024 + ((size_t)schk << 4);
  const size_t bSrc = (size_t)(cb + wid * 32 + srow4) * 1024 + ((size_t)schk << 4);

#define ISSUE_G1(KS)                                                              \
  {                                                                               \
    char* sa = ringB + ((KS)&3) * 32768;                                          \
    char* sb = sa + 16384;                                                        \
    _Pragma("unroll") for (int i = 0; i < 2; ++i) {                               \
      GLL16((const char*)x16 + aSrc + (size_t)i * 16384 + (size_t)(KS)*64,        \
            sa + wid * 2048 + i * 1024);                                          \
      GLL16((const char*)wT + bSrc + (size_t)i * 16384 + (size_t)(KS)*64,         \
            sb + wid * 2048 + i * 1024);                                          \
    }                                                                             \
  }

  ISSUE_G1(0) ISSUE_G1(1) ISSUE_G1(2)  // outstanding: 12 (4/slot/thread)

  f32x4 acc[8][4] = {};

#define GITER(KS, NW)                                                             \
  {                                                                               \
    asm volatile("s_waitcnt vmcnt(" NW ")" ::: "memory");                         \
    __builtin_amdgcn_sched_barrier(0);                                            \
    asm volatile("s_barrier" ::: "memory");                                       \
    if ((KS) + 3 < 16) ISSUE_G1((KS) + 3)                                         \
    char* sa = ringB + ((KS)&3) * 32768;                                          \
    char* sb = sa + 16384;                                                        \
    half8_t a[8], b[4];                                                           \
    _Pragma("unroll") for (int mt = 0; mt < 8; ++mt)                              \
        a[mt] = *(const half8_t*)(sa + (wr * 128 + mt * 16 + lr) * 64 + koff);    \
    _Pragma("unroll") for (int nt = 0; nt < 4; ++nt)                              \
        b[nt] = *(const half8_t*)(sb + (wc * 64 + nt * 16 + lr) * 64 + koff);     \
    __builtin_amdgcn_s_setprio(1);                                                \
    _Pragma("unroll") for (int mt = 0; mt < 8; ++mt)                              \
        _Pragma("unroll") for (int nt = 0; nt < 4; ++nt)                          \
            acc[mt][nt] =                                                         \
                __builtin_amdgcn_mfma_f32_16x16x32_f16(a[mt], b[nt], acc[mt][nt], 0, 0, 0); \
    __builtin_amdgcn_s_setprio(0);                                                \
  }

  // steady outstanding at vmcnt = 12 (slots KS..KS+2) -> vmcnt(8) drains slot KS; tail 4,0
  GITER(0, "8")  GITER(1, "8")  GITER(2, "8")  GITER(3, "8")
  GITER(4, "8")  GITER(5, "8")  GITER(6, "8")  GITER(7, "8")
  GITER(8, "8")  GITER(9, "8")  GITER(10, "8") GITER(11, "8")
  GITER(12, "8") GITER(13, "8") GITER(14, "4") GITER(15, "0")

  if (j == 2) {  // V: key-permuted panels, 8B stores (no LDS reuse needed)
#pragma unroll
    for (int nt = 0; nt < 4; ++nt) {
      const int ch = cb + wc * 64 + nt * 16 + lr;
      const int h = (ch >> 6) & 7, d = ch & 63;
      const float bvs = bias[ch];
#pragma unroll
      for (int mt = 0; mt < 8; ++mt) {
        const int row = m0 + wr * 128 + mt * 16 + g * 4;
        const int wL = row >> 9, n = row & 511;
        _Float16* panel = qkv + ((size_t)(wL * 24 + 16 + h) << 15);
        const int kg = n >> 4, hh = (n >> 2) & 1, e4 = (n & 8) >> 1;
        half4_t pk = {(_Float16)(acc[mt][nt][0] + bvs), (_Float16)(acc[mt][nt][1] + bvs),
                      (_Float16)(acc[mt][nt][2] + bvs), (_Float16)(acc[mt][nt][3] + bvs)};
        *(half4_t*)(panel + ((size_t)(kg * 2 + hh) * 64 + d) * 8 + e4) = pk;
      }
    }
  } else {  // Q/K: acc -> swizzled LDS C-tile (reuse ring) -> coalesced 16B stores
    __syncthreads();  // all slot reads done; safe to reuse ring (vmcnt already 0)
    const float scl = (j == 0) ? 1.44269504f : 1.0f;
    char* CB = ringB;
#pragma unroll
    for (int nt = 0; nt < 4; ++nt) {
      const int chl = wc * 64 + nt * 16 + lr;
      const float bvs = bias[cb + chl];
#pragma unroll
      for (int mt = 0; mt < 8; ++mt) {
#pragma unroll
        for (int r = 0; r < 4; ++r) {
          int nl = wr * 128 + mt * 16 + g * 4 + r;
          *(_Float16*)(CB + nl * 512 + ((chl * 2) ^ ((nl & 7) << 5))) =
              (_Float16)((acc[mt][nt][r] + bvs) * scl);
        }
      }
    }
    __syncthreads();
#pragma unroll
    for (int i = 0; i < 16; ++i) {
      int idx = i * 512 + tid, nl = idx >> 5, c8 = idx & 31;
      half8_t vv = *(const half8_t*)(CB + nl * 512 + ((c8 * 16) ^ ((nl & 7) << 5)));
      int chg = cb + c8 * 8;
      int h = (chg >> 6) & 7, d = chg & 63;
      int ng = m0 + nl, wL = ng >> 9, nn = ng & 511;
      _Float16* panel = qkv + ((size_t)(wL * 24 + j * 8 + h) << 15);
      *(half8_t*)(panel + (size_t)nn * 64 + d) = vv;
    }
  }
}

// ---------------- attention v7: 8-wave blocks, LDS K/V ring, counted vmcnt ----------------
// grid = dim3(nw*8, 2). Block = 8 waves on one (w,h) half (256 q-rows); ring 4 x 8KB.
__global__ __launch_bounds__(512) void attn_win(_Float16* __restrict__ qkv) {
  __shared__ __align__(16) char ring[4 * 8192];
  char* ringB = ring;
  const int tid = threadIdx.x;
  const int l = tid & 63;
  const int wid = tid >> 6;   // 0..7
  const int q32 = l & 31;
  const int h2 = l >> 5;
  const int wh = blockIdx.x;
  const int qc = blockIdx.y;  // 0..1
  const int h = wh & 7;
  const int w = wh >> 3;
  _Float16* Qp = qkv + ((size_t)(w * 24 + h) << 15);
  const _Float16* Kp = qkv + ((size_t)(w * 24 + 8 + h) << 15);
  const _Float16* Vp = qkv + ((size_t)(w * 24 + 16 + h) << 15);
  const int qrow = qc * 256 + wid * 32 + q32;

  const size_t kSrc = (size_t)(l >> 3) * 128 + (size_t)((l & 7) ^ (l >> 3)) * 16;
  const int kof0 = ((0 * 2 + h2) ^ (q32 & 7)) << 4;
  const int kof1 = ((1 * 2 + h2) ^ (q32 & 7)) << 4;
  const int kof2 = ((2 * 2 + h2) ^ (q32 & 7)) << 4;
  const int kof3 = ((3 * 2 + h2) ^ (q32 & 7)) << 4;
  const int voff = 4096 + h2 * 1024 + q32 * 16;

#define ISSUE_SLOT(KT)                                                            \
  {                                                                               \
    char* sb = ringB + ((KT)&3) * 8192;                                           \
    if (wid < 4) {                                                                \
      GLL16((const char*)Kp + (size_t)(KT)*4096 + (size_t)wid * 1024 + kSrc,      \
            sb + wid * 1024);                                                     \
    } else {                                                                      \
      GLL16((const char*)Vp + (size_t)(KT)*4096 + (size_t)(wid - 4) * 1024 + l * 16, \
            sb + 4096 + (wid - 4) * 1024);                                        \
    }                                                                             \
  }

  half8_t qf[4];
#pragma unroll
  for (int j = 0; j < 4; ++j)
    qf[j] = *(const half8_t*)(Qp + (size_t)qrow * 64 + j * 16 + h2 * 8);
  asm volatile("s_waitcnt vmcnt(0)" ::: "memory");

  ISSUE_SLOT(0) ISSUE_SLOT(1) ISSUE_SLOT(2)

  f32x16 o0 = {}, o1 = {};
  float m_run = -1e30f, lsum = 0.f;

#define AITER(KT, NW)                                                             \
  {                                                                               \
    asm volatile("s_waitcnt vmcnt(" NW ")" ::: "memory");                         \
    __builtin_amdgcn_sched_barrier(0);                                            \
    asm volatile("s_barrier" ::: "memory");                                       \
    if ((KT) + 3 < 16) ISSUE_SLOT((KT) + 3)                                       \
    char* sl = ringB + ((KT)&3) * 8192;                                           \
    half8_t kf0 = *(const half8_t*)(sl + q32 * 128 + kof0);                       \
    half8_t kf1 = *(const half8_t*)(sl + q32 * 128 + kof1);                       \
    half8_t kf2 = *(const half8_t*)(sl + q32 * 128 + kof2);                       \
    half8_t kf3 = *(const half8_t*)(sl + q32 * 128 + kof3);                       \
    __builtin_amdgcn_s_setprio(1);                                                \
    f32x16 s = {};                                                                \
    s = __builtin_amdgcn_mfma_f32_32x32x16_f16(kf0, qf[0], s, 0, 0, 0);           \
    s = __builtin_amdgcn_mfma_f32_32x32x16_f16(kf1, qf[1], s, 0, 0, 0);           \
    s = __builtin_amdgcn_mfma_f32_32x32x16_f16(kf2, qf[2], s, 0, 0, 0);           \
    s = __builtin_amdgcn_mfma_f32_32x32x16_f16(kf3, qf[3], s, 0, 0, 0);           \
    __builtin_amdgcn_s_setprio(0);                                                \
    float ma = fmaxf(fmaxf(s[0], s[1]), s[2]);                                    \
    float mb = fmaxf(fmaxf(s[3], s[4]), s[5]);                                    \
    float mc = fmaxf(fmaxf(s[6], s[7]), s[8]);                                    \
    float md = fmaxf(fmaxf(s[9], s[10]), s[11]);                                  \
    float me = fmaxf(fmaxf(s[12], s[13]), s[14]);                                 \
    float mf_ = fmaxf(fmaxf(ma, mb), mc);                                         \
    float mg = fmaxf(fmaxf(md, me), s[15]);                                       \
    float tmax = fmaxf(mf_, mg);                                                  \
    tmax = fmaxf(tmax, __shfl_xor(tmax, 32));                                     \
    if (!__all(tmax <= m_run + 11.5f)) {                                          \
      float mNew = fmaxf(m_run, tmax);                                            \
      float sc = fexp2(m_run - mNew);                                             \
      lsum *= sc;                                                                 \
      _Pragma("unroll") for (int r = 0; r < 16; ++r) { o0[r] *= sc; o1[r] *= sc; }\
      m_run = mNew;                                                               \
    }                                                                             \
    half8_t pf0, pf1;                                                             \
    float tsum = 0.f;                                                             \
    _Pragma("unroll") for (int e = 0; e < 4; ++e) {                               \
      float a0 = fexp2(s[2 * e] - m_run), a1 = fexp2(s[2 * e + 1] - m_run);       \
      tsum += a0 + a1;                                                            \
      ((half2_t*)&pf0)[e] =                                                       \
          __builtin_bit_cast(half2_t, __builtin_amdgcn_cvt_pkrtz(a0, a1));        \
    }                                                                             \
    _Pragma("unroll") for (int e = 0; e < 4; ++e) {                               \
      float a0 = fexp2(s[8 + 2 * e] - m_run), a1 = fexp2(s[9 + 2 * e] - m_run);   \
      tsum += a0 + a1;                                                            \
      ((half2_t*)&pf1)[e] =                                                       \
          __builtin_bit_cast(half2_t, __builtin_amdgcn_cvt_pkrtz(a0, a1));        \
    }                                                                             \
    tsum += __shfl_xor(tsum, 32);                                                 \
    lsum += tsum;                                                                 \
    half8_t vf0 = *(const half8_t*)(sl + voff);                                   \
    half8_t vf1 = *(const half8_t*)(sl + voff + 512);                             \
    half8_t vf2 = *(const half8_t*)(sl + voff + 2048);                            \
    half8_t vf3 = *(const half8_t*)(sl + voff + 2560);                            \
    __builtin_amdgcn_s_setprio(1);                                                \
    o0 = __builtin_amdgcn_mfma_f32_32x32x16_f16(vf0, pf0, o0, 0, 0, 0);           \
    o1 = __builtin_amdgcn_mfma_f32_32x32x16_f16(vf1, pf0, o1, 0, 0, 0);           \
    o0 = __builtin_amdgcn_mfma_f32_32x32x16_f16(vf2, pf1, o0, 0, 0, 0);           \
    o1 = __builtin_amdgcn_mfma_f32_32x32x16_f16(vf3, pf1, o1, 0, 0, 0);           \
    __builtin_amdgcn_s_setprio(0);                                                \
  }

  AITER(0, "2")  AITER(1, "2")  AITER(2, "2")  AITER(3, "2")
  AITER(4, "2")  AITER(5, "2")  AITER(6, "2")  AITER(7, "2")
  AITER(8, "2")  AITER(9, "2")  AITER(10, "2") AITER(11, "2")
  AITER(12, "2") AITER(13, "2") AITER(14, "1") AITER(15, "0")

  const float inv = 1.0f / lsum;
#pragma unroll
  for (int rq = 0; rq < 4; ++rq) {
    half4_t v0, v1;
#pragma unroll
    for (int i = 0; i < 4; ++i) {
      v0[i] = (_Float16)(o0[rq * 4 + i] * inv);
      v1[i] = (_Float16)(o1[rq * 4 + i] * inv);
    }
    *(half4_t*)(Qp + (size_t)qrow * 64 + 8 * rq + 4 * h2) = v0;
    *(half4_t*)(Qp + (size_t)qrow * 64 + 32 + 8 * rq + 4 * h2) = v1;
  }
}

// ---------------- GEMM2: out = attn_out @ Wproj + b, k-prefetched fragments ----------------
__global__ __launch_bounds__(256) void gemm2_proj(
    const _Float16* __restrict__ qkv,
    const _Float16* __restrict__ wpT,
    const float* __restrict__ bias,
    float* __restrict__ out) {
  const int tid = threadIdx.x, l = tid & 63;
  const int wid = tid >> 6, wr = wid >> 1, wc = wid & 1;
  const int lr = l & 15, lk8 = (l >> 4) * 8;
  const int m0 = blockIdx.x * 128, n0 = blockIdx.y * 128;
  size_t aBase[4];
#pragma unroll
  for (int mt = 0; mt < 4; ++mt) {
    int row = m0 + wr * 64 + mt * 16 + lr;
    int wL = row >> 9, n = row & 511;
    aBase[mt] = ((size_t)(wL * 24) << 15) + (size_t)n * 64 + lk8;
  }
  size_t bBase[4];
#pragma unroll
  for (int nt = 0; nt < 4; ++nt)
    bBase[nt] = (size_t)(n0 + wc * 64 + nt * 16 + lr) * 512 + lk8;

  half8_t a[4], b[4];
#pragma unroll
  for (int mt = 0; mt < 4; ++mt) a[mt] = *(const half8_t*)(qkv + aBase[mt]);
#pragma unroll
  for (int nt = 0; nt < 4; ++nt) b[nt] = *(const half8_t*)(wpT + bBase[nt]);

  f32x4 acc[4][4] = {};
#pragma unroll 2
  for (int ks = 0; ks < 16; ++ks) {
    half8_t an[4], bn[4];
    if (ks < 15) {
      const size_t aoff = (size_t)((ks + 1) >> 1) * 32768 + (size_t)((ks + 1) & 1) * 32;
#pragma unroll
      for (int mt = 0; mt < 4; ++mt) an[mt] = *(const half8_t*)(qkv + aBase[mt] + aoff);
#pragma unroll
      for (int nt = 0; nt < 4; ++nt) bn[nt] = *(const half8_t*)(wpT + bBase[nt] + (ks + 1) * 32);
    }
#pragma unroll
    for (int mt = 0; mt < 4; ++mt)
#pragma unroll
      for (int nt = 0; nt < 4; ++nt)
        acc[mt][nt] = __builtin_amdgcn_mfma_f32_16x16x32_f16(a[mt], b[nt], acc[mt][nt], 0, 0, 0);
#pragma unroll
    for (int i = 0; i < 4; ++i) { a[i] = an[i]; b[i] = bn[i]; }
  }
#pragma unroll
  for (int nt = 0; nt < 4; ++nt) {
    int col = n0 + wc * 64 + nt * 16 + lr;
    float bv = bias[col];
#pragma unroll
    for (int mt = 0; mt < 4; ++mt) {
      int row = m0 + wr * 64 + mt * 16 + ((l >> 4) << 2);
#pragma unroll
      for (int r = 0; r < 4; ++r)
        out[(size_t)(row + r) * 512 + col] = acc[mt][nt][r] + bv;
    }
  }
}

extern "C" void kernel_launch(void* const* d_in, const int* in_sizes, int n_in,
                              void* d_out, int out_size, void* d_ws, size_t ws_size,
                              hipStream_t stream) {
  const float* x = (const float*)d_in[0];
  const float* wqkv = (const float*)d_in[1];
  const float* bqkv = (const float*)d_in[2];
  const float* wproj = (const float*)d_in[3];
  const float* bproj = (const float*)d_in[4];
  float* out = (float*)d_out;

  _Float16* wqkvT = (_Float16*)d_ws;
  _Float16* wprojT = wqkvT + (size_t)TC * CDIM;
  _Float16* chunkws = wprojT + (size_t)CDIM * CDIM;
  const size_t fixed = ((size_t)TC * CDIM + (size_t)CDIM * CDIM) * sizeof(_Float16);
  const size_t perwin = ((size_t)NTOK * CDIM + (size_t)24 * 32768) * sizeof(_Float16);
  int nw = 64;
  while (nw > 1 && fixed + (size_t)nw * perwin > ws_size) nw >>= 1;

  prep_weights<<<dim3(256), 256, 0, stream>>>(wqkv, wproj, wqkvT, wprojT);
  for (int wbase = 0; wbase < NWIN; wbase += nw) {
    const float* xc = x + (size_t)wbase * NTOK * CDIM;
    float* oc = out + (size_t)wbase * NTOK * CDIM;
    _Float16* x16 = chunkws;
    _Float16* qkvws = chunkws + (size_t)nw * NTOK * CDIM;
    const int n8 = nw * NTOK * CDIM / 8;
    cvt_x<<<dim3((n8 + 255) / 256), 256, 0, stream>>>(xc, x16, n8);
    gemm1_qkv<<<dim3(nw * 2, 6), 512, 0, stream>>>(x16, wqkvT, bqkv, qkvws);
    attn_win<<<dim3(nw * 8, 2), 512, 0, stream>>>(qkvws);
    gemm2_proj<<<dim3(nw * 4, 4), 256, 0, stream>>>(qkvws, wprojT, bproj, oc);
  }
}